// Round 2
// baseline (455.402 us; speedup 1.0000x reference)
//
#include <hip/hip_runtime.h>

// ---------------- problem constants ----------------
#define B_N 8
#define D_N 512
#define T_N 36
#define HW_N 84
#define THW_N 3024
#define DT_N 4
#define OT_N 32
#define NH_N 4
#define FF_N 128
#define CH_N 32
#define DI_N 336      // demo tokens 4*84
#define OI_N 2688     // obs tokens 32*84
#define CAT_N 420
#define INV_TEMP 0.04419417382415922f   // 1/sqrt(512)
#define BN_EPS 1e-5f
#define INV_CNT (1.0f / 24192.0f)       // 1/(B*THW)

// workspace: float stats[2][1024] at base (sum[512], sumsq[512] per layer),
// then bf16 (short) arena at +8192B.
#define SW_DWQ 0
#define SW_DWK 131072
#define SW_DWV 262144
#define SW_OWQ 393216
#define SW_OWK 524288
#define SW_OWV 655360
#define SW_OWO 786432
#define S_DQ   917504     // [b][336][128] token-major (INV_TEMP folded)
#define S_DK   1261568    // [b][336][128] token-major
#define S_DV   1605632    // [b][128][336] channel-major
#define S_DVA  1949696    // [b][128][336] channel-major
#define S_OQ   2293760    // [b][2688][128] token-major (INV_TEMP folded)
#define S_OK   5046272    // [b][2688][128] token-major
#define S_OV   7798784    // [b][128][2688] channel-major
#define S_OVA  10551296   // [b][32][84][128] token-major
#define S_XBF  13303808   // [b][3024][512] token-major bf16 x

typedef short bf16x8 __attribute__((ext_vector_type(8)));   // 8 bf16 in 4 VGPRs
typedef float f32x4 __attribute__((ext_vector_type(4)));

__device__ __forceinline__ short f2bf(float f) {
    unsigned u = __float_as_uint(f);
    u += 0x7fffu + ((u >> 16) & 1u);          // round-to-nearest-even
    return (short)(u >> 16);
}
__device__ __forceinline__ float bf2f(short s) {
    return __uint_as_float(((unsigned)(unsigned short)s) << 16);
}

// ---------------- weight conversion + stats zero (once per launch) --------
__global__ __launch_bounds__(256) void cvt_w_kernel(
    const float* __restrict__ s0, const float* __restrict__ s1,
    const float* __restrict__ s2, const float* __restrict__ s3,
    const float* __restrict__ s4, const float* __restrict__ s5,
    const float* __restrict__ s6, short* __restrict__ dst,
    float* __restrict__ stats)
{
    const int bid = blockIdx.x;
    if (bid == 0) {   // zero both layers' stats accumulators (2048 floats)
        #pragma unroll
        for (int k = 0; k < 8; ++k) stats[threadIdx.x * 8 + k] = 0.f;
    }
    const int a = bid >> 6, blk = bid & 63;
    const float* src;
    switch (a) {
        case 0: src = s0; break; case 1: src = s1; break;
        case 2: src = s2; break; case 3: src = s3; break;
        case 4: src = s4; break; case 5: src = s5; break;
        default: src = s6;
    }
    const int idx = (blk * 256 + (int)threadIdx.x) * 8;
    float4 f0 = *reinterpret_cast<const float4*>(src + idx);
    float4 f1 = *reinterpret_cast<const float4*>(src + idx + 4);
    bf16x8 pk;
    pk[0] = f2bf(f0.x); pk[1] = f2bf(f0.y); pk[2] = f2bf(f0.z); pk[3] = f2bf(f0.w);
    pk[4] = f2bf(f1.x); pk[5] = f2bf(f1.y); pk[6] = f2bf(f1.z); pk[7] = f2bf(f1.w);
    *reinterpret_cast<bf16x8*>(dst + (size_t)a * 131072 + idx) = pk;
}

// ---------------- input staging: fp32 ch-major -> bf16 token-major -------
__global__ __launch_bounds__(256) void xin_kernel(
    const float* __restrict__ in_f, short* __restrict__ xbf,
    float* __restrict__ stats0)
{
    __shared__ short tile[48][65];
    __shared__ float red_s[16][64];
    __shared__ float red_q[16][64];

    const int bid = blockIdx.x;
    const int b = bid / 504, rem = bid % 504, tt = rem >> 3, cblk = rem & 7;
    const int t0 = tt * 48, c0 = cblk * 64;
    const int tid = threadIdx.x;
    const bool is_demo = (tt < 7);

    #pragma unroll
    for (int l0 = 0; l0 < 768; l0 += 256) {
        int l = l0 + tid;
        int cc = l / 12, tg = l % 12;
        size_t addr = ((size_t)b * D_N + c0 + cc) * THW_N + t0 + tg * 4;
        float4 v = *reinterpret_cast<const float4*>(in_f + addr);
        tile[tg * 4 + 0][cc] = f2bf(v.x);
        tile[tg * 4 + 1][cc] = f2bf(v.y);
        tile[tg * 4 + 2][cc] = f2bf(v.z);
        tile[tg * 4 + 3][cc] = f2bf(v.w);
    }
    __syncthreads();
    float psum[4] = {}, psq[4] = {};
    const int cg = tid & 15;
    #pragma unroll
    for (int l0 = 0; l0 < 768; l0 += 256) {
        int l = l0 + tid;
        int tk = l >> 4;
        short4 s4;
        s4.x = tile[tk][cg * 4 + 0];
        s4.y = tile[tk][cg * 4 + 1];
        s4.z = tile[tk][cg * 4 + 2];
        s4.w = tile[tk][cg * 4 + 3];
        *reinterpret_cast<short4*>(
            xbf + ((size_t)b * THW_N + t0 + tk) * 512 + c0 + cg * 4) = s4;
        if (is_demo) {
            float v0 = bf2f(s4.x), v1 = bf2f(s4.y), v2 = bf2f(s4.z), v3 = bf2f(s4.w);
            psum[0] += v0; psum[1] += v1; psum[2] += v2; psum[3] += v3;
            psq[0] += v0 * v0; psq[1] += v1 * v1; psq[2] += v2 * v2; psq[3] += v3 * v3;
        }
    }
    if (!is_demo) return;
    __syncthreads();
    #pragma unroll
    for (int j = 0; j < 4; ++j) {
        red_s[tid >> 4][cg * 4 + j] = psum[j];
        red_q[tid >> 4][cg * 4 + j] = psq[j];
    }
    __syncthreads();
    if (tid < 64) {
        float s = 0.f, q = 0.f;
        #pragma unroll
        for (int r = 0; r < 16; ++r) { s += red_s[r][tid]; q += red_q[r][tid]; }
        atomicAdd(&stats0[c0 + tid], s);
        atomicAdd(&stats0[512 + c0 + tid], q);
    }
}

// ---------------- fused QKV projection, wave-autonomous bf16 MFMA ---------
// Each wave owns 16 tokens: full K=512 B-fragments held in 64 VGPRs (X read
// once, coalesced). Streams all 3 weight matrices (384 KB, L2-resident on
// every XCD) direct from global as A-fragments into 24 accumulators.
// No LDS, no barriers; 378 blocks x 4 autonomous waves (a wave is entirely
// demo or entirely obs; per-wave divergence is free, no shared state).
__global__ __launch_bounds__(256, 2) void proj_mfma_kernel(
    const short* __restrict__ xbf, short* __restrict__ ws, int layer)
{
    const int tid = threadIdx.x;
    const int lane = tid & 63, wv = tid >> 6;
    const int l15 = lane & 15, q = lane >> 4;

    const int gid = blockIdx.x * 4 + wv;      // 0..1511 (189 tiles per b)
    const int b = gid / 189;
    const int r = gid - b * 189;
    const bool is_demo = (r < 21);
    const int woff = layer * 65536;
    const short* W0 = ws + (is_demo ? SW_DWQ : SW_OWQ) + woff;
    const short* W1 = ws + (is_demo ? SW_DWK : SW_OWK) + woff;
    const short* W2 = ws + (is_demo ? SW_DWV : SW_OWV) + woff;
    const int Ltok = is_demo ? DI_N : OI_N;
    const int tok0 = is_demo ? r * 16 : (r - 21) * 16;
    short* Yq = ws + (is_demo ? S_DQ : S_OQ);
    short* Yk = ws + (is_demo ? S_DK : S_OK);
    short* Yv = ws + (is_demo ? S_DV : S_OV);
    const short* Xb = xbf + ((size_t)b * THW_N + (is_demo ? 0 : DI_N) + tok0) * 512;

    // B-fragments: token = tok0 + l15, k = kc*32 + q*8 .. +8  (64 VGPRs)
    bf16x8 bfr[16];
    #pragma unroll
    for (int kc = 0; kc < 16; ++kc)
        bfr[kc] = *reinterpret_cast<const bf16x8*>(
            Xb + (size_t)l15 * 512 + kc * 32 + q * 8);

    f32x4 acc[3][8] = {};    // [wt][mtile] -> 96 VGPRs
    const short* Wt[3] = {W0, W1, W2};

    #pragma unroll
    for (int kc = 0; kc < 16; ++kc) {
        #pragma unroll
        for (int wt = 0; wt < 3; ++wt) {
            #pragma unroll
            for (int mt = 0; mt < 8; ++mt) {
                bf16x8 afr = *reinterpret_cast<const bf16x8*>(
                    Wt[wt] + (size_t)(mt * 16 + l15) * 512 + kc * 32 + q * 8);
                acc[wt][mt] = __builtin_amdgcn_mfma_f32_16x16x32_bf16(
                    afr, bfr[kc], acc[wt][mt], 0, 0, 0);
            }
        }
    }

    // epilogue: col = token tok0+l15, row = mt*16 + q*4 + r
    const int token = tok0 + l15;
    #pragma unroll
    for (int mt = 0; mt < 8; ++mt) {
        const int mrow = mt * 16 + q * 4;
        f32x4 aq = acc[0][mt] * INV_TEMP;
        short4 s4;
        s4.x = f2bf(aq[0]); s4.y = f2bf(aq[1]); s4.z = f2bf(aq[2]); s4.w = f2bf(aq[3]);
        *reinterpret_cast<short4*>(Yq + ((size_t)b * Ltok + token) * 128 + mrow) = s4;
        f32x4 ak = acc[1][mt];
        s4.x = f2bf(ak[0]); s4.y = f2bf(ak[1]); s4.z = f2bf(ak[2]); s4.w = f2bf(ak[3]);
        *reinterpret_cast<short4*>(Yk + ((size_t)b * Ltok + token) * 128 + mrow) = s4;
        #pragma unroll
        for (int rr = 0; rr < 4; ++rr)
            Yv[((size_t)b * FF_N + mrow + rr) * Ltok + token] = f2bf(acc[2][mt][rr]);
    }
}

// ---------------- demo attention, single-pass bf16 MFMA -------------------
// Block = (b, n, ti, i-half). 192 threads = 3 waves; wave w -> i-tile w of the
// 48-row half. Q/K/V fragments loaded DIRECT from global (token-major dk/dq,
// channel-major dv). Scores for all j (<= 21 tiles, templated) in registers;
// single-pass softmax; one LDS buffer (Pt) + one barrier; PV direct-V.
template<int NT>
__device__ __forceinline__ void demo_core(
    const short* __restrict__ dqS, const short* __restrict__ dkS,
    const short* __restrict__ dvS, short* __restrict__ dvaS,
    short* __restrict__ Pt, int b, int n, int ti, int ih)
{
    constexpr int NTP = (NT + 1) & ~1;        // k-padded tile count for PV
    const int tid = threadIdx.x;
    const int lane = tid & 63, w = tid >> 6;  // w in 0..2
    const int l15 = lane & 15, q = lane >> 4;
    const int jmax = (ti + 1) * 84;

    // QK: A-frag rows i from dk (clamp out-of-frame rows -> finite scores)
    const int irow = ih * 48 + w * 16 + l15;
    const int tokA = ti * 84 + (irow < 84 ? irow : 83);
    bf16x8 afr = *reinterpret_cast<const bf16x8*>(
        dkS + ((size_t)b * DI_N + tokA) * 128 + n * 32 + q * 8);

    f32x4 s[NT];
    #pragma unroll
    for (int nt = 0; nt < NT; ++nt) {
        bf16x8 bfr = *reinterpret_cast<const bf16x8*>(
            dqS + ((size_t)b * DI_N + nt * 16 + l15) * 128 + n * 32 + q * 8);
        f32x4 z = {};
        s[nt] = __builtin_amdgcn_mfma_f32_16x16x32_bf16(afr, bfr, z, 0, 0, 0);
    }

    // softmax over j per row r (rows i = base + q*4 + r, cols l15 within tile)
    const int mstart = jmax - (NT - 1) * 16;  // mask l15 >= mstart in last tile
    #pragma unroll
    for (int r = 0; r < 4; ++r) {
        if (l15 >= mstart) s[NT - 1][r] = -3.0e38f;
        float mx = s[0][r];
        #pragma unroll
        for (int nt = 1; nt < NT; ++nt) mx = fmaxf(mx, s[nt][r]);
        #pragma unroll
        for (int o = 1; o < 16; o <<= 1) mx = fmaxf(mx, __shfl_xor(mx, o));
        float sm = 0.f;
        #pragma unroll
        for (int nt = 0; nt < NT; ++nt) {
            float e = __expf(s[nt][r] - mx);
            s[nt][r] = e; sm += e;
        }
        #pragma unroll
        for (int o = 1; o < 16; o <<= 1) sm += __shfl_xor(sm, o);
        float inv = 1.f / sm;
        #pragma unroll
        for (int nt = 0; nt < NT; ++nt) s[nt][r] *= inv;
    }

    // write normalized P to Pt[i_local][j] (stride 360 -> 2-way-free banks)
    #pragma unroll
    for (int nt = 0; nt < NT; ++nt)
        #pragma unroll
        for (int r = 0; r < 4; ++r)
            Pt[(w * 16 + q * 4 + r) * 360 + nt * 16 + l15] = f2bf(s[nt][r]);
    if (NTP != NT) {   // zero k-pad tile
        #pragma unroll
        for (int r = 0; r < 4; ++r)
            Pt[(w * 16 + q * 4 + r) * 360 + NT * 16 + l15] = 0;
    }
    __syncthreads();

    // PV: wave w -> n-tile it=w (its own 16 i-cols), ct in {0,1} (c-tiles)
    f32x4 oacc[2] = {};
    #pragma unroll
    for (int kk = 0; kk < NTP / 2; ++kk) {
        bf16x8 pb = *reinterpret_cast<const bf16x8*>(
            &Pt[(w * 16 + l15) * 360 + kk * 32 + q * 8]);
        #pragma unroll
        for (int ct = 0; ct < 2; ++ct) {
            bf16x8 va = *reinterpret_cast<const bf16x8*>(
                dvS + ((size_t)b * FF_N + n * 32 + ct * 16 + l15) * DI_N + kk * 32 + q * 8);
            oacc[ct] = __builtin_amdgcn_mfma_f32_16x16x32_bf16(va, pb, oacc[ct], 0, 0, 0);
        }
    }

    // epilogue: c = ct*16 + q*4 + r, i = ih*48 + w*16 + l15
    const int ig = ih * 48 + w * 16 + l15;
    if (ig < 84) {
        #pragma unroll
        for (int ct = 0; ct < 2; ++ct)
            #pragma unroll
            for (int r = 0; r < 4; ++r)
                dvaS[((size_t)b * FF_N + n * 32 + ct * 16 + q * 4 + r) * DI_N + ti * 84 + ig] =
                    f2bf(oacc[ct][r]);
    }
}

__global__ __launch_bounds__(192) void demo_attn_mfma_kernel(const short* __restrict__ ws)
{
    __shared__ short Pt[48 * 360];   // 34.56 KB

    const short* dqS = ws + S_DQ;
    const short* dkS = ws + S_DK;
    const short* dvS = ws + S_DV;
    short* dvaS = const_cast<short*>(ws) + S_DVA;

    const int bid = blockIdx.x;      // ((b*4 + n)*4 + ti)*2 + ih
    const int ih = bid & 1, ti = (bid >> 1) & 3;
    const int n = (bid >> 3) & 3, b = bid >> 5;

    switch (ti) {
        case 0: demo_core<6>(dqS, dkS, dvS, dvaS, Pt, b, n, ti, ih); break;
        case 1: demo_core<11>(dqS, dkS, dvS, dvaS, Pt, b, n, ti, ih); break;
        case 2: demo_core<16>(dqS, dkS, dvS, dvaS, Pt, b, n, ti, ih); break;
        default: demo_core<21>(dqS, dkS, dvS, dvaS, Pt, b, n, ti, ih); break;
    }
}

// ---------------- obs attention, bf16 MFMA ----------------
__global__ __launch_bounds__(256, 4) void obs_attn_mfma_kernel(const short* __restrict__ ws)
{
    __shared__ short Qt[96 * 40];
    __shared__ short Kt[64 * 40];
    __shared__ short Vs[32 * 72];
    __shared__ short Pt[96 * 72];

    const short* dkS = ws + S_DK;
    const short* dvaS = ws + S_DVA;
    const short* oqS = ws + S_OQ;
    const short* okS = ws + S_OK;
    const short* ovS = ws + S_OV;
    short* ovaS = const_cast<short*>(ws) + S_OVA;

    const int bid = blockIdx.x;
    const int b = bid >> 7, rem = bid & 127, t = rem >> 2, n = rem & 3;

    const int tid = threadIdx.x;
    const int lane = tid & 63, wv = tid >> 6;
    const int l15 = lane & 15, q = lane >> 4;

    for (int l = tid; l < 384; l += 256) {
        int i = l >> 2, c0 = (l & 3) * 8;
        bf16x8 pk = {0,0,0,0,0,0,0,0};
        if (i < HW_N)
            pk = *reinterpret_cast<const bf16x8*>(
                oqS + ((size_t)b * OI_N + t * 84 + i) * 128 + n * 32 + c0);
        *reinterpret_cast<bf16x8*>(&Qt[i * 40 + c0]) = pk;
    }

    const int pv_mt = wv & 1;
    const int pv_nb = wv >> 1;
    f32x4 oacc[3] = {};

    for (int jc = 0; jc < 448; jc += 64) {
        __syncthreads();
        {
            int jl = tid >> 2, c0 = (tid & 3) * 8;
            int jg = jc + jl;
            bf16x8 pk = {0,0,0,0,0,0,0,0};
            if (jg < DI_N)
                pk = *reinterpret_cast<const bf16x8*>(
                    dkS + ((size_t)b * DI_N + jg) * 128 + n * 32 + c0);
            else if (jg < CAT_N)
                pk = *reinterpret_cast<const bf16x8*>(
                    okS + ((size_t)b * OI_N + t * 84 + (jg - DI_N)) * 128 + n * 32 + c0);
            *reinterpret_cast<bf16x8*>(&Kt[jl * 40 + c0]) = pk;
        }
        {
            int c = tid >> 3, j0 = (tid & 7) * 8;
            int jg0 = jc + j0;
            const short* dvaRow = dvaS + ((size_t)b * FF_N + n * 32 + c) * DI_N;
            const short* ovRow = ovS + ((size_t)b * FF_N + n * 32 + c) * OI_N + t * 84;
            bf16x8 pk;
            if (jg0 + 8 <= DI_N) {
                pk = *reinterpret_cast<const bf16x8*>(dvaRow + jg0);
            } else if (jg0 >= DI_N && jg0 + 8 <= CAT_N) {
                short4 lo = *reinterpret_cast<const short4*>(ovRow + (jg0 - DI_N));
                short4 hi = *reinterpret_cast<const short4*>(ovRow + (jg0 - DI_N) + 4);
                pk[0]=lo.x; pk[1]=lo.y; pk[2]=lo.z; pk[3]=lo.w;
                pk[4]=hi.x; pk[5]=hi.y; pk[6]=hi.z; pk[7]=hi.w;
            } else {
                #pragma unroll
                for (int p = 0; p < 8; ++p) {
                    int jg = jg0 + p;
                    pk[p] = (jg < DI_N) ? dvaRow[jg]
                          : ((jg < CAT_N) ? ovRow[jg - DI_N] : (short)0);
                }
            }
            *reinterpret_cast<bf16x8*>(&Vs[c * 72 + j0]) = pk;
        }
        __syncthreads();

        f32x4 s[6];
        bf16x8 afr = *reinterpret_cast<const bf16x8*>(&Kt[(wv * 16 + l15) * 40 + q * 8]);
        #pragma unroll
        for (int nt = 0; nt < 6; ++nt) {
            bf16x8 bfr = *reinterpret_cast<const bf16x8*>(&Qt[(nt * 16 + l15) * 40 + q * 8]);
            f32x4 z = {};
            s[nt] = __builtin_amdgcn_mfma_f32_16x16x32_bf16(afr, bfr, z, 0, 0, 0);
        }
        float inv[4];
        #pragma unroll
        for (int r = 0; r < 4; ++r) {
            if (l15 >= 4) s[5][r] = -3.0e38f;
            float m2 = s[0][r];
            #pragma unroll
            for (int nt2 = 1; nt2 < 6; ++nt2) m2 = fmaxf(m2, s[nt2][r]);
            #pragma unroll
            for (int o = 1; o < 16; o <<= 1) m2 = fmaxf(m2, __shfl_xor(m2, o));
            float sm = 0.f;
            #pragma unroll
            for (int nt2 = 0; nt2 < 6; ++nt2) { float e = __expf(s[nt2][r] - m2); s[nt2][r] = e; sm += e; }
            #pragma unroll
            for (int o = 1; o < 16; o <<= 1) sm += __shfl_xor(sm, o);
            inv[r] = 1.f / sm;
        }
        #pragma unroll
        for (int nt = 0; nt < 6; ++nt) {
            short4 pk4;
            pk4.x = f2bf(s[nt][0] * inv[0]);
            pk4.y = f2bf(s[nt][1] * inv[1]);
            pk4.z = f2bf(s[nt][2] * inv[2]);
            pk4.w = f2bf(s[nt][3] * inv[3]);
            *reinterpret_cast<short4*>(&Pt[(nt * 16 + l15) * 72 + wv * 16 + q * 4]) = pk4;
        }
        __syncthreads();

        #pragma unroll
        for (int kk = 0; kk < 2; ++kk) {
            bf16x8 va = *reinterpret_cast<const bf16x8*>(&Vs[(pv_mt * 16 + l15) * 72 + kk * 32 + q * 8]);
            #pragma unroll
            for (int u = 0; u < 3; ++u) {
                int nt = pv_nb + u * 2;
                bf16x8 pb = *reinterpret_cast<const bf16x8*>(&Pt[(nt * 16 + l15) * 72 + kk * 32 + q * 8]);
                oacc[u] = __builtin_amdgcn_mfma_f32_16x16x32_bf16(va, pb, oacc[u], 0, 0, 0);
            }
        }
    }

    #pragma unroll
    for (int u = 0; u < 3; ++u) {
        int i = (pv_nb + u * 2) * 16 + l15;
        if (i < HW_N) {
            short4 st;
            st.x = f2bf(oacc[u][0]); st.y = f2bf(oacc[u][1]);
            st.z = f2bf(oacc[u][2]); st.w = f2bf(oacc[u][3]);
            *reinterpret_cast<short4*>(
                ovaS + (((size_t)b * OT_N + t) * 84 + i) * 128 + n * 32 + pv_mt * 16 + q * 4) = st;
        }
    }
}

// ---------------- output projection + ReLU + residual (bf16 x) + stats ----
// Wave-autonomous: each wave owns 32 output channels (full K=128 of Wo held
// in 32 VGPRs, loaded once from L2) and streams 48 tokens (3 n-tiles) with
// B-fragments loaded DIRECT from global ova (token-major -> coalesced
// 16B/lane). No LDS staging, no barriers in the compute loop.
__global__ __launch_bounds__(256) void outproj_mfma_kernel(
    short* __restrict__ xbf, const short* __restrict__ ws, int layer,
    float* __restrict__ stats)
{
    __shared__ float redS[4][32];
    __shared__ float redQ[4][32];

    const int bid = blockIdx.x;
    const int t8 = bid & 7;           // XCD id (round-robin dispatch)
    const int rr = bid >> 3;
    const int c32 = rr & 15;          // channel block: 32 chans
    const int tc = rr >> 4;           // 0..13
    const int tchunk = tc * 8 + t8;   // 0..111, 192 tokens each
    const int o0 = c32 * 32;

    const int tid = threadIdx.x;
    const int lane = tid & 63, wv = tid >> 6;
    const int l15 = lane & 15, q = lane >> 4;

    // this wave's 48 tokens (global flat token id over [B][2688])
    const int g0 = tchunk * 192 + wv * 48;
    const int b = g0 / OI_N;                    // 2688 % 192 == 0 -> constant
    const size_t xbase = (size_t)(g0 + DI_N * (b + 1)) * 512 + o0;

    const short* Wo = ws + SW_OWO + layer * 65536;
    const short* ova = ws + S_OVA;

    // weights in registers: afr[mtile][kchunk], row m = o0+mt*16+l15,
    // k elements kc*32 + q*8 .. +8 (matches 16x16x32 A-frag layout)
    bf16x8 afr[2][4];
    #pragma unroll
    for (int mt = 0; mt < 2; ++mt)
        #pragma unroll
        for (int kc = 0; kc < 4; ++kc)
            afr[mt][kc] = *reinterpret_cast<const bf16x8*>(
                Wo + (size_t)(o0 + mt * 16 + l15) * FF_N + kc * 32 + q * 8);

    float csum[2][4] = {}, csq[2][4] = {};

    #pragma unroll
    for (int nt = 0; nt < 3; ++nt) {
        const int g = g0 + nt * 16;
        // B-frag direct from global: row n = token g+l15, k = kc*32 + q*8
        const short* ovaT = ova + (size_t)(g + l15) * FF_N + q * 8;
        bf16x8 bfr[4];
        #pragma unroll
        for (int kc = 0; kc < 4; ++kc)
            bfr[kc] = *reinterpret_cast<const bf16x8*>(ovaT + kc * 32);

        f32x4 acc[2] = {};
        #pragma unroll
        for (int kc = 0; kc < 4; ++kc) {
            acc[0] = __builtin_amdgcn_mfma_f32_16x16x32_bf16(afr[0][kc], bfr[kc], acc[0], 0, 0, 0);
            acc[1] = __builtin_amdgcn_mfma_f32_16x16x32_bf16(afr[1][kc], bfr[kc], acc[1], 0, 0, 0);
        }

        // RMW x: token = g+l15 (acc col), chans o0+mt*16+q*4..+3 (acc rows)
        #pragma unroll
        for (int mt = 0; mt < 2; ++mt) {
            short* p = xbf + xbase + (size_t)(nt * 16 + l15) * 512 + mt * 16 + q * 4;
            short4 old4 = *reinterpret_cast<short4*>(p);
            float ov[4] = {bf2f(old4.x), bf2f(old4.y), bf2f(old4.z), bf2f(old4.w)};
            short4 nw;
            short* nwp = &nw.x;
            #pragma unroll
            for (int r = 0; r < 4; ++r) {
                float v = acc[mt][r];
                float y = ov[r] + (v > 0.f ? v : 0.f);
                short ybf = f2bf(y);
                nwp[r] = ybf;
                float yr = bf2f(ybf);
                csum[mt][r] += yr;
                csq[mt][r] += yr * yr;
            }
            *reinterpret_cast<short4*>(p) = nw;
        }
    }

    // stats: reduce over the 16 token-lanes, then across the 4 waves via LDS
    #pragma unroll
    for (int mt = 0; mt < 2; ++mt) {
        #pragma unroll
        for (int r = 0; r < 4; ++r) {
            float s = csum[mt][r], qq = csq[mt][r];
            #pragma unroll
            for (int o = 1; o < 16; o <<= 1) {
                s += __shfl_xor(s, o);
                qq += __shfl_xor(qq, o);
            }
            if (l15 == 0) {
                redS[wv][mt * 16 + q * 4 + r] = s;
                redQ[wv][mt * 16 + q * 4 + r] = qq;
            }
        }
    }
    __syncthreads();
    if (tid < 32) {
        float s = redS[0][tid] + redS[1][tid] + redS[2][tid] + redS[3][tid];
        float qq = redQ[0][tid] + redQ[1][tid] + redQ[2][tid] + redQ[3][tid];
        atomicAdd(&stats[o0 + tid], s);
        atomicAdd(&stats[512 + o0 + tid], qq);
    }
}

// ---------------- BN in place on bf16 xbf + demo-stats for next layer -----
__global__ __launch_bounds__(256) void bn_mid_kernel(
    short* __restrict__ xbf, const float* __restrict__ stats,
    const float* __restrict__ gamma, const float* __restrict__ beta,
    float* __restrict__ stats_next)
{
    __shared__ float red_s[4][512];
    __shared__ float red_q[4][512];

    const int bid = blockIdx.x;
    const int b = bid / 63, tt = bid % 63;
    const int t0 = tt * 48;
    const bool is_demo = (tt < 7);
    const int tid = threadIdx.x;
    const int chg = tid & 63;
    const int trow = tid >> 6;

    float mean[8], rs[8], g[8], bb[8];
    #pragma unroll
    for (int j = 0; j < 8; ++j) {
        int c = chg * 8 + j;
        float m = stats[c] * INV_CNT;
        float var = stats[512 + c] * INV_CNT - m * m;
        mean[j] = m;
        rs[j] = rsqrtf(var + BN_EPS);
        g[j] = gamma[c];
        bb[j] = beta[c];
    }

    float psum[8] = {}, psq[8] = {};
    #pragma unroll
    for (int it = 0; it < 12; ++it) {
        int tok = t0 + it * 4 + trow;
        short* p = xbf + ((size_t)b * THW_N + tok) * 512 + chg * 8;
        bf16x8 v = *reinterpret_cast<bf16x8*>(p);
        bf16x8 w;
        #pragma unroll
        for (int j = 0; j < 8; ++j) {
            float y = g[j] * (bf2f(v[j]) - mean[j]) * rs[j] + bb[j];
            short yb = f2bf(y);
            w[j] = yb;
            if (is_demo) {
                float yr = bf2f(yb);
                psum[j] += yr; psq[j] += yr * yr;
            }
        }
        *reinterpret_cast<bf16x8*>(p) = w;
    }
    if (!is_demo) return;
    #pragma unroll
    for (int j = 0; j < 8; ++j) {
        red_s[trow][chg * 8 + j] = psum[j];
        red_q[trow][chg * 8 + j] = psq[j];
    }
    __syncthreads();
    #pragma unroll
    for (int h = 0; h < 2; ++h) {
        int c = tid + h * 256;
        float s = red_s[0][c] + red_s[1][c] + red_s[2][c] + red_s[3][c];
        float qq = red_q[0][c] + red_q[1][c] + red_q[2][c] + red_q[3][c];
        atomicAdd(&stats_next[c], s);
        atomicAdd(&stats_next[512 + c], qq);
    }
}

// ---------------- final BN -> fp32 channel-major d_out --------------------
__global__ __launch_bounds__(256) void bn_out_kernel(
    const short* __restrict__ xbf, float* __restrict__ out_f,
    const float* __restrict__ stats,
    const float* __restrict__ gamma, const float* __restrict__ beta)
{
    __shared__ float tile[48][65];

    const int bid = blockIdx.x;
    const int b = bid / 504, rem = bid % 504, tt = rem >> 3, cblk = rem & 7;
    const int t0 = tt * 48, c0 = cblk * 64;
    const int tid = threadIdx.x;
    const int cg = tid & 15;

    float mean[4], rs[4], g[4], bb[4];
    #pragma unroll
    for (int j = 0; j < 4; ++j) {
        int c = c0 + cg * 4 + j;
        float m = stats[c] * INV_CNT;
        float var = stats[512 + c] * INV_CNT - m * m;
        mean[j] = m; rs[j] = rsqrtf(var + BN_EPS);
        g[j] = gamma[c]; bb[j] = beta[c];
    }

    #pragma unroll
    for (int l0 = 0; l0 < 768; l0 += 256) {
        int l = l0 + tid;
        int tok = l >> 4;
        short4 v = *reinterpret_cast<const short4*>(
            xbf + ((size_t)b * THW_N + t0 + tok) * 512 + c0 + cg * 4);
        tile[tok][cg * 4 + 0] = g[0] * (bf2f(v.x) - mean[0]) * rs[0] + bb[0];
        tile[tok][cg * 4 + 1] = g[1] * (bf2f(v.y) - mean[1]) * rs[1] + bb[1];
        tile[tok][cg * 4 + 2] = g[2] * (bf2f(v.z) - mean[2]) * rs[2] + bb[2];
        tile[tok][cg * 4 + 3] = g[3] * (bf2f(v.w) - mean[3]) * rs[3] + bb[3];
    }
    __syncthreads();
    #pragma unroll
    for (int l0 = 0; l0 < 768; l0 += 256) {
        int l = l0 + tid;
        int cc = l / 12, tg = l % 12;
        float4 o;
        o.x = tile[tg * 4 + 0][cc];
        o.y = tile[tg * 4 + 1][cc];
        o.z = tile[tg * 4 + 2][cc];
        o.w = tile[tg * 4 + 3][cc];
        *reinterpret_cast<float4*>(
            out_f + ((size_t)b * D_N + c0 + cc) * THW_N + t0 + tg * 4) = o;
    }
}

// ---------------- launch ----------------
extern "C" void kernel_launch(void* const* d_in, const int* in_sizes, int n_in,
                              void* d_out, int out_size, void* d_ws, size_t ws_size,
                              hipStream_t stream)
{
    const float* inp  = (const float*)d_in[0];
    const float* dwq  = (const float*)d_in[1];
    const float* dwk  = (const float*)d_in[2];
    const float* dwv  = (const float*)d_in[3];
    const float* owq  = (const float*)d_in[5];
    const float* owk  = (const float*)d_in[6];
    const float* owv  = (const float*)d_in[7];
    const float* owo  = (const float*)d_in[8];
    const float* gam  = (const float*)d_in[9];
    const float* bet  = (const float*)d_in[10];
    float* x  = (float*)d_out;
    float* stats = (float*)d_ws;          // [2][1024]
    short* wsS = (short*)(stats + 2048);
    short* xbf = wsS + S_XBF;

    cvt_w_kernel<<<448, 256, 0, stream>>>(dwq, dwk, dwv, owq, owk, owv, owo, wsS, stats);
    xin_kernel<<<4032, 256, 0, stream>>>(inp, xbf, stats);

    for (int layer = 0; layer < 2; ++layer) {
        float* stL = stats + layer * 1024;
        size_t coff = (size_t)layer * D_N;
        proj_mfma_kernel<<<378, 256, 0, stream>>>(xbf, wsS, layer);
        demo_attn_mfma_kernel<<<256, 192, 0, stream>>>(wsS);
        obs_attn_mfma_kernel<<<1024, 256, 0, stream>>>(wsS);
        outproj_mfma_kernel<<<1792, 256, 0, stream>>>(xbf, wsS, layer, stL);
        if (layer == 0) {
            bn_mid_kernel<<<504, 256, 0, stream>>>(
                xbf, stL, gam + coff, bet + coff, stats + 1024);
        } else {
            bn_out_kernel<<<4032, 256, 0, stream>>>(
                xbf, x, stL, gam + coff, bet + coff);
        }
    }
    (void)in_sizes; (void)n_in; (void)out_size; (void)ws_size;
}

// Round 3
// 341.914 us; speedup vs baseline: 1.3319x; 1.3319x over previous
//
#include <hip/hip_runtime.h>

// ---------------- problem constants ----------------
#define B_N 8
#define D_N 512
#define T_N 36
#define HW_N 84
#define THW_N 3024
#define DT_N 4
#define OT_N 32
#define NH_N 4
#define FF_N 128
#define CH_N 32
#define DI_N 336      // demo tokens 4*84
#define OI_N 2688     // obs tokens 32*84
#define CAT_N 420
#define INV_TEMP 0.04419417382415922f   // 1/sqrt(512)
#define BN_EPS 1e-5f
#define INV_CNT (1.0f / 24192.0f)       // 1/(B*THW)

// workspace: float stats[2][1024] at base (sum[512], sumsq[512] per layer),
// then bf16 (short) arena at +8192B.
#define SW_DWQ 0
#define SW_DWK 131072
#define SW_DWV 262144
#define SW_OWQ 393216
#define SW_OWK 524288
#define SW_OWV 655360
#define SW_OWO 786432
#define S_DQ   917504     // [b][336][128] token-major (INV_TEMP folded)
#define S_DK   1261568    // [b][336][128] token-major
#define S_DV   1605632    // [b][128][336] channel-major
#define S_DVA  1949696    // [b][128][336] channel-major
#define S_OQ   2293760    // [b][2688][128] token-major (INV_TEMP folded)
#define S_OK   5046272    // [b][2688][128] token-major
#define S_OV   7798784    // [b][128][2688] channel-major
#define S_OVA  10551296   // [b][32][84][128] token-major
#define S_XBF  13303808   // [b][3024][512] token-major bf16 x

typedef short bf16x8 __attribute__((ext_vector_type(8)));   // 8 bf16 in 4 VGPRs
typedef float f32x4 __attribute__((ext_vector_type(4)));
typedef unsigned int u32;

// 16B global->LDS DMA: per-lane global src, wave-uniform LDS base (+lane*16)
#define GLD16(SRC, DST) __builtin_amdgcn_global_load_lds( \
    (const __attribute__((address_space(1))) u32*)(SRC), \
    (__attribute__((address_space(3))) u32*)(DST), 16, 0, 0)

__device__ __forceinline__ short f2bf(float f) {
    unsigned u = __float_as_uint(f);
    u += 0x7fffu + ((u >> 16) & 1u);          // round-to-nearest-even
    return (short)(u >> 16);
}
__device__ __forceinline__ float bf2f(short s) {
    return __uint_as_float(((unsigned)(unsigned short)s) << 16);
}

// ---------------- weight conversion + stats zero (once per launch) --------
__global__ __launch_bounds__(256) void cvt_w_kernel(
    const float* __restrict__ s0, const float* __restrict__ s1,
    const float* __restrict__ s2, const float* __restrict__ s3,
    const float* __restrict__ s4, const float* __restrict__ s5,
    const float* __restrict__ s6, short* __restrict__ dst,
    float* __restrict__ stats)
{
    const int bid = blockIdx.x;
    if (bid == 0) {   // zero both layers' stats accumulators (2048 floats)
        #pragma unroll
        for (int k = 0; k < 8; ++k) stats[threadIdx.x * 8 + k] = 0.f;
    }
    const int a = bid >> 6, blk = bid & 63;
    const float* src;
    switch (a) {
        case 0: src = s0; break; case 1: src = s1; break;
        case 2: src = s2; break; case 3: src = s3; break;
        case 4: src = s4; break; case 5: src = s5; break;
        default: src = s6;
    }
    const int idx = (blk * 256 + (int)threadIdx.x) * 8;
    float4 f0 = *reinterpret_cast<const float4*>(src + idx);
    float4 f1 = *reinterpret_cast<const float4*>(src + idx + 4);
    bf16x8 pk;
    pk[0] = f2bf(f0.x); pk[1] = f2bf(f0.y); pk[2] = f2bf(f0.z); pk[3] = f2bf(f0.w);
    pk[4] = f2bf(f1.x); pk[5] = f2bf(f1.y); pk[6] = f2bf(f1.z); pk[7] = f2bf(f1.w);
    *reinterpret_cast<bf16x8*>(dst + (size_t)a * 131072 + idx) = pk;
}

// ---------------- input staging: fp32 ch-major -> bf16 token-major -------
__global__ __launch_bounds__(256) void xin_kernel(
    const float* __restrict__ in_f, short* __restrict__ xbf,
    float* __restrict__ stats0)
{
    __shared__ short tile[48][65];
    __shared__ float red_s[16][64];
    __shared__ float red_q[16][64];

    const int bid = blockIdx.x;
    const int b = bid / 504, rem = bid % 504, tt = rem >> 3, cblk = rem & 7;
    const int t0 = tt * 48, c0 = cblk * 64;
    const int tid = threadIdx.x;
    const bool is_demo = (tt < 7);

    #pragma unroll
    for (int l0 = 0; l0 < 768; l0 += 256) {
        int l = l0 + tid;
        int cc = l / 12, tg = l % 12;
        size_t addr = ((size_t)b * D_N + c0 + cc) * THW_N + t0 + tg * 4;
        float4 v = *reinterpret_cast<const float4*>(in_f + addr);
        tile[tg * 4 + 0][cc] = f2bf(v.x);
        tile[tg * 4 + 1][cc] = f2bf(v.y);
        tile[tg * 4 + 2][cc] = f2bf(v.z);
        tile[tg * 4 + 3][cc] = f2bf(v.w);
    }
    __syncthreads();
    float psum[4] = {}, psq[4] = {};
    const int cg = tid & 15;
    #pragma unroll
    for (int l0 = 0; l0 < 768; l0 += 256) {
        int l = l0 + tid;
        int tk = l >> 4;
        short4 s4;
        s4.x = tile[tk][cg * 4 + 0];
        s4.y = tile[tk][cg * 4 + 1];
        s4.z = tile[tk][cg * 4 + 2];
        s4.w = tile[tk][cg * 4 + 3];
        *reinterpret_cast<short4*>(
            xbf + ((size_t)b * THW_N + t0 + tk) * 512 + c0 + cg * 4) = s4;
        if (is_demo) {
            float v0 = bf2f(s4.x), v1 = bf2f(s4.y), v2 = bf2f(s4.z), v3 = bf2f(s4.w);
            psum[0] += v0; psum[1] += v1; psum[2] += v2; psum[3] += v3;
            psq[0] += v0 * v0; psq[1] += v1 * v1; psq[2] += v2 * v2; psq[3] += v3 * v3;
        }
    }
    if (!is_demo) return;
    __syncthreads();
    #pragma unroll
    for (int j = 0; j < 4; ++j) {
        red_s[tid >> 4][cg * 4 + j] = psum[j];
        red_q[tid >> 4][cg * 4 + j] = psq[j];
    }
    __syncthreads();
    if (tid < 64) {
        float s = 0.f, q = 0.f;
        #pragma unroll
        for (int r = 0; r < 16; ++r) { s += red_s[r][tid]; q += red_q[r][tid]; }
        atomicAdd(&stats0[c0 + tid], s);
        atomicAdd(&stats0[512 + c0 + tid], q);
    }
}

// ---------------- fused QKV projection, LDS-staged async bf16 MFMA --------
// Block = (b, ct token-tile of 48, mh M-half of 64 rows); 4 waves, wave wv
// owns A-rows [wv*16, wv*16+16) of the half. Weights+X staged into LDS with
// global_load_lds 16B DMA (no VGPR roundtrip, no staging VALU); logical LDS
// layout [kc][m] identical to the verified round-1 kernel -- only the
// chunk->lane assignment changed to be lane-linear (DMA requirement).
// BK=64 -> 8 K-steps (16 barriers). LDS 30KB; grid 1008 ~= 4 blocks/CU.
__global__ __launch_bounds__(256) void proj_mfma_kernel(
    const short* __restrict__ xbf, short* __restrict__ ws, int layer)
{
    __shared__ short As[3][4096];   // per wt: chunk (kc*64+m) of 8 shorts, kc<8,m<64
    __shared__ short Bs[3072];      // chunk (kc*48+n), kc<8, n<48

    const int tid = threadIdx.x;
    const int lane = tid & 63, wv = tid >> 6;
    const int l15 = lane & 15, q = lane >> 4;

    const int bid = blockIdx.x;
    const int mh = bid & 1;
    const int rem = bid >> 1;
    const int b = rem / 63, ct = rem - b * 63;
    const bool is_demo = (ct < 7);
    const int woff = layer * 65536;
    const short* W0 = ws + (is_demo ? SW_DWQ : SW_OWQ) + woff;
    const short* W1 = ws + (is_demo ? SW_DWK : SW_OWK) + woff;
    const short* W2 = ws + (is_demo ? SW_DWV : SW_OWV) + woff;
    const int Ltok = is_demo ? DI_N : OI_N;
    const int colL = is_demo ? ct * 48 : (ct - 7) * 48;
    short* Yq = ws + (is_demo ? S_DQ : S_OQ);
    short* Yk = ws + (is_demo ? S_DK : S_OK);
    short* Yv = ws + (is_demo ? S_DV : S_OV);
    const short* Xb = xbf + ((size_t)b * THW_N + (is_demo ? 0 : DI_N) + colL) * 512;

    // per-lane DMA source bases (k0-independent).
    // As chunk c = h*256 + wv*64 + lane  ->  kc = h*4+wv, m = lane.
    const short* rp[3];
    rp[0] = W0 + (size_t)(mh * 64 + lane) * 512;
    rp[1] = W1 + (size_t)(mh * 64 + lane) * 512;
    rp[2] = W2 + (size_t)(mh * 64 + lane) * 512;
    // Bs chunk c = h*192 + wv*64 + lane (wv<3) -> kc = c/48, n = c%48.
    const short* bp[2];
    #pragma unroll
    for (int h = 0; h < 2; ++h) {
        int c = h * 192 + wv * 64 + lane;
        bp[h] = Xb + (size_t)(c % 48) * 512 + (c / 48) * 8;
    }

    f32x4 acc[3][3] = {};

    for (int k0 = 0; k0 < D_N; k0 += 64) {
        __syncthreads();
        #pragma unroll
        for (int h = 0; h < 2; ++h) {
            #pragma unroll
            for (int wt = 0; wt < 3; ++wt)
                GLD16(rp[wt] + k0 + (h * 4 + wv) * 8,
                      &As[wt][(h * 256 + wv * 64) * 8]);
        }
        if (wv < 3) {
            GLD16(bp[0] + k0, &Bs[(wv * 64) * 8]);
            GLD16(bp[1] + k0, &Bs[(192 + wv * 64) * 8]);
        }
        __syncthreads();   // compiler drains vmcnt(0) here -> DMA complete

        #pragma unroll
        for (int kk = 0; kk < 2; ++kk) {
            const int kc = kk * 4 + q;
            bf16x8 bfr[3];
            #pragma unroll
            for (int nt = 0; nt < 3; ++nt)
                bfr[nt] = *reinterpret_cast<const bf16x8*>(
                    &Bs[(kc * 48 + nt * 16 + l15) * 8]);
            #pragma unroll
            for (int wt = 0; wt < 3; ++wt) {
                bf16x8 afr = *reinterpret_cast<const bf16x8*>(
                    &As[wt][(kc * 64 + wv * 16 + l15) * 8]);
                #pragma unroll
                for (int nt = 0; nt < 3; ++nt)
                    acc[wt][nt] = __builtin_amdgcn_mfma_f32_16x16x32_bf16(
                        afr, bfr[nt], acc[wt][nt], 0, 0, 0);
            }
        }
    }

    // epilogue: out row = mh*64 + wv*16 + q*4 + r, col = token colL+nt*16+l15
    const int mrow = mh * 64 + wv * 16 + q * 4;
    #pragma unroll
    for (int nt = 0; nt < 3; ++nt) {
        const int token = colL + nt * 16 + l15;
        f32x4 aq = acc[0][nt] * INV_TEMP;
        short4 s4;
        s4.x = f2bf(aq[0]); s4.y = f2bf(aq[1]); s4.z = f2bf(aq[2]); s4.w = f2bf(aq[3]);
        *reinterpret_cast<short4*>(Yq + ((size_t)b * Ltok + token) * 128 + mrow) = s4;
        f32x4 ak = acc[1][nt];
        s4.x = f2bf(ak[0]); s4.y = f2bf(ak[1]); s4.z = f2bf(ak[2]); s4.w = f2bf(ak[3]);
        *reinterpret_cast<short4*>(Yk + ((size_t)b * Ltok + token) * 128 + mrow) = s4;
        #pragma unroll
        for (int rr = 0; rr < 4; ++rr)
            Yv[((size_t)b * FF_N + mrow + rr) * Ltok + token] = f2bf(acc[2][nt][rr]);
    }
}

// ---------------- demo attention, single-pass bf16 MFMA -------------------
// Block = (b, n, ti, i-half). 192 threads = 3 waves; wave w -> i-tile w of the
// 48-row half. Q/K/V fragments loaded DIRECT from global (token-major dk/dq,
// channel-major dv). Scores for all j (<= 21 tiles, templated) in registers;
// single-pass softmax; one LDS buffer (Pt) + one barrier; PV direct-V.
template<int NT>
__device__ __forceinline__ void demo_core(
    const short* __restrict__ dqS, const short* __restrict__ dkS,
    const short* __restrict__ dvS, short* __restrict__ dvaS,
    short* __restrict__ Pt, int b, int n, int ti, int ih)
{
    constexpr int NTP = (NT + 1) & ~1;        // k-padded tile count for PV
    const int tid = threadIdx.x;
    const int lane = tid & 63, w = tid >> 6;  // w in 0..2
    const int l15 = lane & 15, q = lane >> 4;
    const int jmax = (ti + 1) * 84;

    // QK: A-frag rows i from dk (clamp out-of-frame rows -> finite scores)
    const int irow = ih * 48 + w * 16 + l15;
    const int tokA = ti * 84 + (irow < 84 ? irow : 83);
    bf16x8 afr = *reinterpret_cast<const bf16x8*>(
        dkS + ((size_t)b * DI_N + tokA) * 128 + n * 32 + q * 8);

    f32x4 s[NT];
    #pragma unroll
    for (int nt = 0; nt < NT; ++nt) {
        bf16x8 bfr = *reinterpret_cast<const bf16x8*>(
            dqS + ((size_t)b * DI_N + nt * 16 + l15) * 128 + n * 32 + q * 8);
        f32x4 z = {};
        s[nt] = __builtin_amdgcn_mfma_f32_16x16x32_bf16(afr, bfr, z, 0, 0, 0);
    }

    // softmax over j per row r (rows i = base + q*4 + r, cols l15 within tile)
    const int mstart = jmax - (NT - 1) * 16;  // mask l15 >= mstart in last tile
    #pragma unroll
    for (int r = 0; r < 4; ++r) {
        if (l15 >= mstart) s[NT - 1][r] = -3.0e38f;
        float mx = s[0][r];
        #pragma unroll
        for (int nt = 1; nt < NT; ++nt) mx = fmaxf(mx, s[nt][r]);
        #pragma unroll
        for (int o = 1; o < 16; o <<= 1) mx = fmaxf(mx, __shfl_xor(mx, o));
        float sm = 0.f;
        #pragma unroll
        for (int nt = 0; nt < NT; ++nt) {
            float e = __expf(s[nt][r] - mx);
            s[nt][r] = e; sm += e;
        }
        #pragma unroll
        for (int o = 1; o < 16; o <<= 1) sm += __shfl_xor(sm, o);
        float inv = 1.f / sm;
        #pragma unroll
        for (int nt = 0; nt < NT; ++nt) s[nt][r] *= inv;
    }

    // write normalized P to Pt[i_local][j] (stride 360 -> 2-way-free banks)
    #pragma unroll
    for (int nt = 0; nt < NT; ++nt)
        #pragma unroll
        for (int r = 0; r < 4; ++r)
            Pt[(w * 16 + q * 4 + r) * 360 + nt * 16 + l15] = f2bf(s[nt][r]);
    if (NTP != NT) {   // zero k-pad tile
        #pragma unroll
        for (int r = 0; r < 4; ++r)
            Pt[(w * 16 + q * 4 + r) * 360 + NT * 16 + l15] = 0;
    }
    __syncthreads();

    // PV: wave w -> n-tile it=w (its own 16 i-cols), ct in {0,1} (c-tiles)
    f32x4 oacc[2] = {};
    #pragma unroll
    for (int kk = 0; kk < NTP / 2; ++kk) {
        bf16x8 pb = *reinterpret_cast<const bf16x8*>(
            &Pt[(w * 16 + l15) * 360 + kk * 32 + q * 8]);
        #pragma unroll
        for (int ct = 0; ct < 2; ++ct) {
            bf16x8 va = *reinterpret_cast<const bf16x8*>(
                dvS + ((size_t)b * FF_N + n * 32 + ct * 16 + l15) * DI_N + kk * 32 + q * 8);
            oacc[ct] = __builtin_amdgcn_mfma_f32_16x16x32_bf16(va, pb, oacc[ct], 0, 0, 0);
        }
    }

    // epilogue: c = ct*16 + q*4 + r, i = ih*48 + w*16 + l15
    const int ig = ih * 48 + w * 16 + l15;
    if (ig < 84) {
        #pragma unroll
        for (int ct = 0; ct < 2; ++ct)
            #pragma unroll
            for (int r = 0; r < 4; ++r)
                dvaS[((size_t)b * FF_N + n * 32 + ct * 16 + q * 4 + r) * DI_N + ti * 84 + ig] =
                    f2bf(oacc[ct][r]);
    }
}

__global__ __launch_bounds__(192) void demo_attn_mfma_kernel(const short* __restrict__ ws)
{
    __shared__ short Pt[48 * 360];   // 34.56 KB

    const short* dqS = ws + S_DQ;
    const short* dkS = ws + S_DK;
    const short* dvS = ws + S_DV;
    short* dvaS = const_cast<short*>(ws) + S_DVA;

    const int bid = blockIdx.x;      // ((b*4 + n)*4 + ti)*2 + ih
    const int ih = bid & 1, ti = (bid >> 1) & 3;
    const int n = (bid >> 3) & 3, b = bid >> 5;

    switch (ti) {
        case 0: demo_core<6>(dqS, dkS, dvS, dvaS, Pt, b, n, ti, ih); break;
        case 1: demo_core<11>(dqS, dkS, dvS, dvaS, Pt, b, n, ti, ih); break;
        case 2: demo_core<16>(dqS, dkS, dvS, dvaS, Pt, b, n, ti, ih); break;
        default: demo_core<21>(dqS, dkS, dvS, dvaS, Pt, b, n, ti, ih); break;
    }
}

// ---------------- obs attention, bf16 MFMA ----------------
__global__ __launch_bounds__(256, 4) void obs_attn_mfma_kernel(const short* __restrict__ ws)
{
    __shared__ short Qt[96 * 40];
    __shared__ short Kt[64 * 40];
    __shared__ short Vs[32 * 72];
    __shared__ short Pt[96 * 72];

    const short* dkS = ws + S_DK;
    const short* dvaS = ws + S_DVA;
    const short* oqS = ws + S_OQ;
    const short* okS = ws + S_OK;
    const short* ovS = ws + S_OV;
    short* ovaS = const_cast<short*>(ws) + S_OVA;

    const int bid = blockIdx.x;
    const int b = bid >> 7, rem = bid & 127, t = rem >> 2, n = rem & 3;

    const int tid = threadIdx.x;
    const int lane = tid & 63, wv = tid >> 6;
    const int l15 = lane & 15, q = lane >> 4;

    for (int l = tid; l < 384; l += 256) {
        int i = l >> 2, c0 = (l & 3) * 8;
        bf16x8 pk = {0,0,0,0,0,0,0,0};
        if (i < HW_N)
            pk = *reinterpret_cast<const bf16x8*>(
                oqS + ((size_t)b * OI_N + t * 84 + i) * 128 + n * 32 + c0);
        *reinterpret_cast<bf16x8*>(&Qt[i * 40 + c0]) = pk;
    }

    const int pv_mt = wv & 1;
    const int pv_nb = wv >> 1;
    f32x4 oacc[3] = {};

    for (int jc = 0; jc < 448; jc += 64) {
        __syncthreads();
        {
            int jl = tid >> 2, c0 = (tid & 3) * 8;
            int jg = jc + jl;
            bf16x8 pk = {0,0,0,0,0,0,0,0};
            if (jg < DI_N)
                pk = *reinterpret_cast<const bf16x8*>(
                    dkS + ((size_t)b * DI_N + jg) * 128 + n * 32 + c0);
            else if (jg < CAT_N)
                pk = *reinterpret_cast<const bf16x8*>(
                    okS + ((size_t)b * OI_N + t * 84 + (jg - DI_N)) * 128 + n * 32 + c0);
            *reinterpret_cast<bf16x8*>(&Kt[jl * 40 + c0]) = pk;
        }
        {
            int c = tid >> 3, j0 = (tid & 7) * 8;
            int jg0 = jc + j0;
            const short* dvaRow = dvaS + ((size_t)b * FF_N + n * 32 + c) * DI_N;
            const short* ovRow = ovS + ((size_t)b * FF_N + n * 32 + c) * OI_N + t * 84;
            bf16x8 pk;
            if (jg0 + 8 <= DI_N) {
                pk = *reinterpret_cast<const bf16x8*>(dvaRow + jg0);
            } else if (jg0 >= DI_N && jg0 + 8 <= CAT_N) {
                short4 lo = *reinterpret_cast<const short4*>(ovRow + (jg0 - DI_N));
                short4 hi = *reinterpret_cast<const short4*>(ovRow + (jg0 - DI_N) + 4);
                pk[0]=lo.x; pk[1]=lo.y; pk[2]=lo.z; pk[3]=lo.w;
                pk[4]=hi.x; pk[5]=hi.y; pk[6]=hi.z; pk[7]=hi.w;
            } else {
                #pragma unroll
                for (int p = 0; p < 8; ++p) {
                    int jg = jg0 + p;
                    pk[p] = (jg < DI_N) ? dvaRow[jg]
                          : ((jg < CAT_N) ? ovRow[jg - DI_N] : (short)0);
                }
            }
            *reinterpret_cast<bf16x8*>(&Vs[c * 72 + j0]) = pk;
        }
        __syncthreads();

        f32x4 s[6];
        bf16x8 afr = *reinterpret_cast<const bf16x8*>(&Kt[(wv * 16 + l15) * 40 + q * 8]);
        #pragma unroll
        for (int nt = 0; nt < 6; ++nt) {
            bf16x8 bfr = *reinterpret_cast<const bf16x8*>(&Qt[(nt * 16 + l15) * 40 + q * 8]);
            f32x4 z = {};
            s[nt] = __builtin_amdgcn_mfma_f32_16x16x32_bf16(afr, bfr, z, 0, 0, 0);
        }
        float inv[4];
        #pragma unroll
        for (int r = 0; r < 4; ++r) {
            if (l15 >= 4) s[5][r] = -3.0e38f;
            float m2 = s[0][r];
            #pragma unroll
            for (int nt2 = 1; nt2 < 6; ++nt2) m2 = fmaxf(m2, s[nt2][r]);
            #pragma unroll
            for (int o = 1; o < 16; o <<= 1) m2 = fmaxf(m2, __shfl_xor(m2, o));
            float sm = 0.f;
            #pragma unroll
            for (int nt2 = 0; nt2 < 6; ++nt2) { float e = __expf(s[nt2][r] - m2); s[nt2][r] = e; sm += e; }
            #pragma unroll
            for (int o = 1; o < 16; o <<= 1) sm += __shfl_xor(sm, o);
            inv[r] = 1.f / sm;
        }
        #pragma unroll
        for (int nt = 0; nt < 6; ++nt) {
            short4 pk4;
            pk4.x = f2bf(s[nt][0] * inv[0]);
            pk4.y = f2bf(s[nt][1] * inv[1]);
            pk4.z = f2bf(s[nt][2] * inv[2]);
            pk4.w = f2bf(s[nt][3] * inv[3]);
            *reinterpret_cast<short4*>(&Pt[(nt * 16 + l15) * 72 + wv * 16 + q * 4]) = pk4;
        }
        __syncthreads();

        #pragma unroll
        for (int kk = 0; kk < 2; ++kk) {
            bf16x8 va = *reinterpret_cast<const bf16x8*>(&Vs[(pv_mt * 16 + l15) * 72 + kk * 32 + q * 8]);
            #pragma unroll
            for (int u = 0; u < 3; ++u) {
                int nt = pv_nb + u * 2;
                bf16x8 pb = *reinterpret_cast<const bf16x8*>(&Pt[(nt * 16 + l15) * 72 + kk * 32 + q * 8]);
                oacc[u] = __builtin_amdgcn_mfma_f32_16x16x32_bf16(va, pb, oacc[u], 0, 0, 0);
            }
        }
    }

    #pragma unroll
    for (int u = 0; u < 3; ++u) {
        int i = (pv_nb + u * 2) * 16 + l15;
        if (i < HW_N) {
            short4 st;
            st.x = f2bf(oacc[u][0]); st.y = f2bf(oacc[u][1]);
            st.z = f2bf(oacc[u][2]); st.w = f2bf(oacc[u][3]);
            *reinterpret_cast<short4*>(
                ovaS + (((size_t)b * OT_N + t) * 84 + i) * 128 + n * 32 + pv_mt * 16 + q * 4) = st;
        }
    }
}

// ---------------- output projection + ReLU + residual (bf16 x) + stats ----
// Wave-autonomous: each wave owns 32 output channels (full K=128 of Wo held
// in 32 VGPRs, loaded once from L2) and streams 48 tokens (3 n-tiles) with
// B-fragments loaded DIRECT from global ova (token-major -> coalesced
// 16B/lane). No LDS staging, no barriers in the compute loop.
__global__ __launch_bounds__(256) void outproj_mfma_kernel(
    short* __restrict__ xbf, const short* __restrict__ ws, int layer,
    float* __restrict__ stats)
{
    __shared__ float redS[4][32];
    __shared__ float redQ[4][32];

    const int bid = blockIdx.x;
    const int t8 = bid & 7;           // XCD id (round-robin dispatch)
    const int rr = bid >> 3;
    const int c32 = rr & 15;          // channel block: 32 chans
    const int tc = rr >> 4;           // 0..13
    const int tchunk = tc * 8 + t8;   // 0..111, 192 tokens each
    const int o0 = c32 * 32;

    const int tid = threadIdx.x;
    const int lane = tid & 63, wv = tid >> 6;
    const int l15 = lane & 15, q = lane >> 4;

    // this wave's 48 tokens (global flat token id over [B][2688])
    const int g0 = tchunk * 192 + wv * 48;
    const int b = g0 / OI_N;                    // 2688 % 192 == 0 -> constant
    const size_t xbase = (size_t)(g0 + DI_N * (b + 1)) * 512 + o0;

    const short* Wo = ws + SW_OWO + layer * 65536;
    const short* ova = ws + S_OVA;

    // weights in registers: afr[mtile][kchunk], row m = o0+mt*16+l15,
    // k elements kc*32 + q*8 .. +8 (matches 16x16x32 A-frag layout)
    bf16x8 afr[2][4];
    #pragma unroll
    for (int mt = 0; mt < 2; ++mt)
        #pragma unroll
        for (int kc = 0; kc < 4; ++kc)
            afr[mt][kc] = *reinterpret_cast<const bf16x8*>(
                Wo + (size_t)(o0 + mt * 16 + l15) * FF_N + kc * 32 + q * 8);

    float csum[2][4] = {}, csq[2][4] = {};

    #pragma unroll
    for (int nt = 0; nt < 3; ++nt) {
        const int g = g0 + nt * 16;
        // B-frag direct from global: row n = token g+l15, k = kc*32 + q*8
        const short* ovaT = ova + (size_t)(g + l15) * FF_N + q * 8;
        bf16x8 bfr[4];
        #pragma unroll
        for (int kc = 0; kc < 4; ++kc)
            bfr[kc] = *reinterpret_cast<const bf16x8*>(ovaT + kc * 32);

        f32x4 acc[2] = {};
        #pragma unroll
        for (int kc = 0; kc < 4; ++kc) {
            acc[0] = __builtin_amdgcn_mfma_f32_16x16x32_bf16(afr[0][kc], bfr[kc], acc[0], 0, 0, 0);
            acc[1] = __builtin_amdgcn_mfma_f32_16x16x32_bf16(afr[1][kc], bfr[kc], acc[1], 0, 0, 0);
        }

        // RMW x: token = g+l15 (acc col), chans o0+mt*16+q*4..+3 (acc rows)
        #pragma unroll
        for (int mt = 0; mt < 2; ++mt) {
            short* p = xbf + xbase + (size_t)(nt * 16 + l15) * 512 + mt * 16 + q * 4;
            short4 old4 = *reinterpret_cast<short4*>(p);
            float ov[4] = {bf2f(old4.x), bf2f(old4.y), bf2f(old4.z), bf2f(old4.w)};
            short4 nw;
            short* nwp = &nw.x;
            #pragma unroll
            for (int r = 0; r < 4; ++r) {
                float v = acc[mt][r];
                float y = ov[r] + (v > 0.f ? v : 0.f);
                short ybf = f2bf(y);
                nwp[r] = ybf;
                float yr = bf2f(ybf);
                csum[mt][r] += yr;
                csq[mt][r] += yr * yr;
            }
            *reinterpret_cast<short4*>(p) = nw;
        }
    }

    // stats: reduce over the 16 token-lanes, then across the 4 waves via LDS
    #pragma unroll
    for (int mt = 0; mt < 2; ++mt) {
        #pragma unroll
        for (int r = 0; r < 4; ++r) {
            float s = csum[mt][r], qq = csq[mt][r];
            #pragma unroll
            for (int o = 1; o < 16; o <<= 1) {
                s += __shfl_xor(s, o);
                qq += __shfl_xor(qq, o);
            }
            if (l15 == 0) {
                redS[wv][mt * 16 + q * 4 + r] = s;
                redQ[wv][mt * 16 + q * 4 + r] = qq;
            }
        }
    }
    __syncthreads();
    if (tid < 32) {
        float s = redS[0][tid] + redS[1][tid] + redS[2][tid] + redS[3][tid];
        float qq = redQ[0][tid] + redQ[1][tid] + redQ[2][tid] + redQ[3][tid];
        atomicAdd(&stats[o0 + tid], s);
        atomicAdd(&stats[512 + o0 + tid], qq);
    }
}

// ---------------- BN in place on bf16 xbf + demo-stats for next layer -----
__global__ __launch_bounds__(256) void bn_mid_kernel(
    short* __restrict__ xbf, const float* __restrict__ stats,
    const float* __restrict__ gamma, const float* __restrict__ beta,
    float* __restrict__ stats_next)
{
    __shared__ float red_s[4][512];
    __shared__ float red_q[4][512];

    const int bid = blockIdx.x;
    const int b = bid / 63, tt = bid % 63;
    const int t0 = tt * 48;
    const bool is_demo = (tt < 7);
    const int tid = threadIdx.x;
    const int chg = tid & 63;
    const int trow = tid >> 6;

    float mean[8], rs[8], g[8], bb[8];
    #pragma unroll
    for (int j = 0; j < 8; ++j) {
        int c = chg * 8 + j;
        float m = stats[c] * INV_CNT;
        float var = stats[512 + c] * INV_CNT - m * m;
        mean[j] = m;
        rs[j] = rsqrtf(var + BN_EPS);
        g[j] = gamma[c];
        bb[j] = beta[c];
    }

    float psum[8] = {}, psq[8] = {};
    #pragma unroll
    for (int it = 0; it < 12; ++it) {
        int tok = t0 + it * 4 + trow;
        short* p = xbf + ((size_t)b * THW_N + tok) * 512 + chg * 8;
        bf16x8 v = *reinterpret_cast<bf16x8*>(p);
        bf16x8 w;
        #pragma unroll
        for (int j = 0; j < 8; ++j) {
            float y = g[j] * (bf2f(v[j]) - mean[j]) * rs[j] + bb[j];
            short yb = f2bf(y);
            w[j] = yb;
            if (is_demo) {
                float yr = bf2f(yb);
                psum[j] += yr; psq[j] += yr * yr;
            }
        }
        *reinterpret_cast<bf16x8*>(p) = w;
    }
    if (!is_demo) return;
    #pragma unroll
    for (int j = 0; j < 8; ++j) {
        red_s[trow][chg * 8 + j] = psum[j];
        red_q[trow][chg * 8 + j] = psq[j];
    }
    __syncthreads();
    #pragma unroll
    for (int h = 0; h < 2; ++h) {
        int c = tid + h * 256;
        float s = red_s[0][c] + red_s[1][c] + red_s[2][c] + red_s[3][c];
        float qq = red_q[0][c] + red_q[1][c] + red_q[2][c] + red_q[3][c];
        atomicAdd(&stats_next[c], s);
        atomicAdd(&stats_next[512 + c], qq);
    }
}

// ---------------- final BN -> fp32 channel-major d_out --------------------
__global__ __launch_bounds__(256) void bn_out_kernel(
    const short* __restrict__ xbf, float* __restrict__ out_f,
    const float* __restrict__ stats,
    const float* __restrict__ gamma, const float* __restrict__ beta)
{
    __shared__ float tile[48][65];

    const int bid = blockIdx.x;
    const int b = bid / 504, rem = bid % 504, tt = rem >> 3, cblk = rem & 7;
    const int t0 = tt * 48, c0 = cblk * 64;
    const int tid = threadIdx.x;
    const int cg = tid & 15;

    float mean[4], rs[4], g[4], bb[4];
    #pragma unroll
    for (int j = 0; j < 4; ++j) {
        int c = c0 + cg * 4 + j;
        float m = stats[c] * INV_CNT;
        float var = stats[512 + c] * INV_CNT - m * m;
        mean[j] = m; rs[j] = rsqrtf(var + BN_EPS);
        g[j] = gamma[c]; bb[j] = beta[c];
    }

    #pragma unroll
    for (int l0 = 0; l0 < 768; l0 += 256) {
        int l = l0 + tid;
        int tok = l >> 4;
        short4 v = *reinterpret_cast<const short4*>(
            xbf + ((size_t)b * THW_N + t0 + tok) * 512 + c0 + cg * 4);
        tile[tok][cg * 4 + 0] = g[0] * (bf2f(v.x) - mean[0]) * rs[0] + bb[0];
        tile[tok][cg * 4 + 1] = g[1] * (bf2f(v.y) - mean[1]) * rs[1] + bb[1];
        tile[tok][cg * 4 + 2] = g[2] * (bf2f(v.z) - mean[2]) * rs[2] + bb[2];
        tile[tok][cg * 4 + 3] = g[3] * (bf2f(v.w) - mean[3]) * rs[3] + bb[3];
    }
    __syncthreads();
    #pragma unroll
    for (int l0 = 0; l0 < 768; l0 += 256) {
        int l = l0 + tid;
        int cc = l / 12, tg = l % 12;
        float4 o;
        o.x = tile[tg * 4 + 0][cc];
        o.y = tile[tg * 4 + 1][cc];
        o.z = tile[tg * 4 + 2][cc];
        o.w = tile[tg * 4 + 3][cc];
        *reinterpret_cast<float4*>(
            out_f + ((size_t)b * D_N + c0 + cc) * THW_N + t0 + tg * 4) = o;
    }
}

// ---------------- launch ----------------
extern "C" void kernel_launch(void* const* d_in, const int* in_sizes, int n_in,
                              void* d_out, int out_size, void* d_ws, size_t ws_size,
                              hipStream_t stream)
{
    const float* inp  = (const float*)d_in[0];
    const float* dwq  = (const float*)d_in[1];
    const float* dwk  = (const float*)d_in[2];
    const float* dwv  = (const float*)d_in[3];
    const float* owq  = (const float*)d_in[5];
    const float* owk  = (const float*)d_in[6];
    const float* owv  = (const float*)d_in[7];
    const float* owo  = (const float*)d_in[8];
    const float* gam  = (const float*)d_in[9];
    const float* bet  = (const float*)d_in[10];
    float* x  = (float*)d_out;
    float* stats = (float*)d_ws;          // [2][1024]
    short* wsS = (short*)(stats + 2048);
    short* xbf = wsS + S_XBF;

    cvt_w_kernel<<<448, 256, 0, stream>>>(dwq, dwk, dwv, owq, owk, owv, owo, wsS, stats);
    xin_kernel<<<4032, 256, 0, stream>>>(inp, xbf, stats);

    for (int layer = 0; layer < 2; ++layer) {
        float* stL = stats + layer * 1024;
        size_t coff = (size_t)layer * D_N;
        proj_mfma_kernel<<<1008, 256, 0, stream>>>(xbf, wsS, layer);
        demo_attn_mfma_kernel<<<256, 192, 0, stream>>>(wsS);
        obs_attn_mfma_kernel<<<1024, 256, 0, stream>>>(wsS);
        outproj_mfma_kernel<<<1792, 256, 0, stream>>>(xbf, wsS, layer, stL);
        if (layer == 0) {
            bn_mid_kernel<<<504, 256, 0, stream>>>(
                xbf, stL, gam + coff, bet + coff, stats + 1024);
        } else {
            bn_out_kernel<<<4032, 256, 0, stream>>>(
                xbf, x, stL, gam + coff, bet + coff);
        }
    }
    (void)in_sizes; (void)n_in; (void)out_size; (void)ws_size;
}

// Round 4
// 313.719 us; speedup vs baseline: 1.4516x; 1.0899x over previous
//
#include <hip/hip_runtime.h>

// ---------------- problem constants ----------------
#define B_N 8
#define D_N 512
#define T_N 36
#define HW_N 84
#define THW_N 3024
#define DT_N 4
#define OT_N 32
#define NH_N 4
#define FF_N 128
#define CH_N 32
#define DI_N 336      // demo tokens 4*84
#define OI_N 2688     // obs tokens 32*84
#define CAT_N 420
#define INV_TEMP 0.04419417382415922f   // 1/sqrt(512)
#define BN_EPS 1e-5f
#define INV_CNT (1.0f / 24192.0f)       // 1/(B*THW)

// workspace: float stats[2][1024] at base (sum[512], sumsq[512] per layer),
// then bf16 (short) arena at +8192B.
#define SW_DWQ 0
#define SW_DWK 131072
#define SW_DWV 262144
#define SW_OWQ 393216
#define SW_OWK 524288
#define SW_OWV 655360
#define SW_OWO 786432
#define S_DQ   917504     // [b][336][128] token-major (INV_TEMP folded)
#define S_DK   1261568    // [b][336][128] token-major
#define S_DV   1605632    // [b][128][336] channel-major
#define S_DVA  1949696    // [b][128][336] channel-major
#define S_OQ   2293760    // [b][2688][128] token-major (INV_TEMP folded)
#define S_OK   5046272    // [b][2688][128] token-major
#define S_OV   7798784    // [b][128][2688] channel-major
#define S_OVA  10551296   // [b][32][84][128] token-major
#define S_XBF  13303808   // [b][3024][512] token-major bf16 x

typedef short bf16x8 __attribute__((ext_vector_type(8)));   // 8 bf16 in 4 VGPRs
typedef float f32x4 __attribute__((ext_vector_type(4)));
typedef unsigned int u32;

// 16B global->LDS DMA: per-lane global src, wave-uniform LDS base (+lane*16)
#define GLD16(SRC, DST) __builtin_amdgcn_global_load_lds( \
    (const __attribute__((address_space(1))) u32*)(SRC), \
    (__attribute__((address_space(3))) u32*)(DST), 16, 0, 0)

__device__ __forceinline__ short f2bf(float f) {
    unsigned u = __float_as_uint(f);
    u += 0x7fffu + ((u >> 16) & 1u);          // round-to-nearest-even
    return (short)(u >> 16);
}
__device__ __forceinline__ float bf2f(short s) {
    return __uint_as_float(((unsigned)(unsigned short)s) << 16);
}

// ---------------- weight conversion + stats zero (once per launch) --------
// QKV weights (a<6) are stored in proj's LDS-staging order so the DMA source
// is CONTIGUOUS (base + lane*16): [layer][panel p*2+mh][kc<8][m<64][8bf16],
// p = k/64 (K-panel), mh = M-half, kc = (k/8)%8, m = row%64.
// owo (a==6) stays row-major [layer][512][128] for outproj fragments.
__global__ __launch_bounds__(256) void cvt_w_kernel(
    const float* __restrict__ s0, const float* __restrict__ s1,
    const float* __restrict__ s2, const float* __restrict__ s3,
    const float* __restrict__ s4, const float* __restrict__ s5,
    const float* __restrict__ s6, short* __restrict__ dst,
    float* __restrict__ stats)
{
    const int bid = blockIdx.x;
    if (bid == 0) {   // zero both layers' stats accumulators (2048 floats)
        #pragma unroll
        for (int k = 0; k < 8; ++k) stats[threadIdx.x * 8 + k] = 0.f;
    }
    const int a = bid >> 6, blk = bid & 63;
    const float* src;
    switch (a) {
        case 0: src = s0; break; case 1: src = s1; break;
        case 2: src = s2; break; case 3: src = s3; break;
        case 4: src = s4; break; case 5: src = s5; break;
        default: src = s6;
    }
    const int idx = (blk * 256 + (int)threadIdx.x) * 8;
    float4 f0 = *reinterpret_cast<const float4*>(src + idx);
    float4 f1 = *reinterpret_cast<const float4*>(src + idx + 4);
    bf16x8 pk;
    pk[0] = f2bf(f0.x); pk[1] = f2bf(f0.y); pk[2] = f2bf(f0.z); pk[3] = f2bf(f0.w);
    pk[4] = f2bf(f1.x); pk[5] = f2bf(f1.y); pk[6] = f2bf(f1.z); pk[7] = f2bf(f1.w);
    size_t dstoff;
    if (a < 6) {
        const int layer = idx >> 16;
        const int w = idx & 65535;
        const int mg = w >> 9;           // row 0..127
        const int k  = w & 511;          // col (chunk-aligned, k%8==0)
        const int p  = k >> 6;           // K-panel 0..7
        const int kc = (k >> 3) & 7;     // chunk-in-panel 0..7
        const int mh = mg >> 6;          // M-half
        const int m  = mg & 63;
        dstoff = (size_t)layer * 65536 +
                 (size_t)(((p * 2 + mh) * 8 + kc) * 64 + m) * 8;
    } else {
        dstoff = idx;
    }
    *reinterpret_cast<bf16x8*>(dst + (size_t)a * 131072 + dstoff) = pk;
}

// ---------------- input staging: fp32 ch-major -> bf16 token-major -------
__global__ __launch_bounds__(256) void xin_kernel(
    const float* __restrict__ in_f, short* __restrict__ xbf,
    float* __restrict__ stats0)
{
    __shared__ short tile[48][65];
    __shared__ float red_s[16][64];
    __shared__ float red_q[16][64];

    const int bid = blockIdx.x;
    const int b = bid / 504, rem = bid % 504, tt = rem >> 3, cblk = rem & 7;
    const int t0 = tt * 48, c0 = cblk * 64;
    const int tid = threadIdx.x;
    const bool is_demo = (tt < 7);

    #pragma unroll
    for (int l0 = 0; l0 < 768; l0 += 256) {
        int l = l0 + tid;
        int cc = l / 12, tg = l % 12;
        size_t addr = ((size_t)b * D_N + c0 + cc) * THW_N + t0 + tg * 4;
        float4 v = *reinterpret_cast<const float4*>(in_f + addr);
        tile[tg * 4 + 0][cc] = f2bf(v.x);
        tile[tg * 4 + 1][cc] = f2bf(v.y);
        tile[tg * 4 + 2][cc] = f2bf(v.z);
        tile[tg * 4 + 3][cc] = f2bf(v.w);
    }
    __syncthreads();
    float psum[4] = {}, psq[4] = {};
    const int cg = tid & 15;
    #pragma unroll
    for (int l0 = 0; l0 < 768; l0 += 256) {
        int l = l0 + tid;
        int tk = l >> 4;
        short4 s4;
        s4.x = tile[tk][cg * 4 + 0];
        s4.y = tile[tk][cg * 4 + 1];
        s4.z = tile[tk][cg * 4 + 2];
        s4.w = tile[tk][cg * 4 + 3];
        *reinterpret_cast<short4*>(
            xbf + ((size_t)b * THW_N + t0 + tk) * 512 + c0 + cg * 4) = s4;
        if (is_demo) {
            float v0 = bf2f(s4.x), v1 = bf2f(s4.y), v2 = bf2f(s4.z), v3 = bf2f(s4.w);
            psum[0] += v0; psum[1] += v1; psum[2] += v2; psum[3] += v3;
            psq[0] += v0 * v0; psq[1] += v1 * v1; psq[2] += v2 * v2; psq[3] += v3 * v3;
        }
    }
    if (!is_demo) return;
    __syncthreads();
    #pragma unroll
    for (int j = 0; j < 4; ++j) {
        red_s[tid >> 4][cg * 4 + j] = psum[j];
        red_q[tid >> 4][cg * 4 + j] = psq[j];
    }
    __syncthreads();
    if (tid < 64) {
        float s = 0.f, q = 0.f;
        #pragma unroll
        for (int r = 0; r < 16; ++r) { s += red_s[r][tid]; q += red_q[r][tid]; }
        atomicAdd(&stats0[c0 + tid], s);
        atomicAdd(&stats0[512 + c0 + tid], q);
    }
}

// ---------------- fused QKV projection, LDS-staged async bf16 MFMA --------
// Block = (b, ct token-tile of 48, mh M-half of 64 rows); 4 waves. Weights
// pre-permuted by cvt_w into the exact LDS chunk order, so each GLD16 streams
// 1KB CONTIGUOUS global bytes (base + lane*16) -> minimal L2 transactions.
// BK=64 -> 8 K-steps. LDS 30KB; grid 1008 ~= 4 blocks/CU.
__global__ __launch_bounds__(256) void proj_mfma_kernel(
    const short* __restrict__ xbf, short* __restrict__ ws, int layer)
{
    __shared__ short As[3][4096];   // per wt: chunk (kc*64+m) of 8 shorts, kc<8,m<64
    __shared__ short Bs[3072];      // chunk (kc*48+n), kc<8, n<48

    const int tid = threadIdx.x;
    const int lane = tid & 63, wv = tid >> 6;
    const int l15 = lane & 15, q = lane >> 4;

    const int bid = blockIdx.x;
    const int mh = bid & 1;
    const int rem = bid >> 1;
    const int b = rem / 63, ct = rem - b * 63;
    const bool is_demo = (ct < 7);
    const int woff = layer * 65536;
    const short* W0 = ws + (is_demo ? SW_DWQ : SW_OWQ) + woff;
    const short* W1 = ws + (is_demo ? SW_DWK : SW_OWK) + woff;
    const short* W2 = ws + (is_demo ? SW_DWV : SW_OWV) + woff;
    const int Ltok = is_demo ? DI_N : OI_N;
    const int colL = is_demo ? ct * 48 : (ct - 7) * 48;
    short* Yq = ws + (is_demo ? S_DQ : S_OQ);
    short* Yk = ws + (is_demo ? S_DK : S_OK);
    short* Yv = ws + (is_demo ? S_DV : S_OV);
    const short* Xb = xbf + ((size_t)b * THW_N + (is_demo ? 0 : DI_N) + colL) * 512;

    // staged-weight DMA source: panel (p*2+mh) of 4096 shorts; chunk within
    // panel = h*256 + wv*64 + lane  (lane*16B contiguous).
    const short* rp[3];
    rp[0] = W0 + (size_t)mh * 4096 + lane * 8;
    rp[1] = W1 + (size_t)mh * 4096 + lane * 8;
    rp[2] = W2 + (size_t)mh * 4096 + lane * 8;
    // Bs chunk c = h*192 + wv*64 + lane (wv<3) -> kc = c/48, n = c%48.
    const short* bp[2];
    #pragma unroll
    for (int h = 0; h < 2; ++h) {
        int c = h * 192 + wv * 64 + lane;
        bp[h] = Xb + (size_t)(c % 48) * 512 + (c / 48) * 8;
    }

    f32x4 acc[3][3] = {};

    for (int k0 = 0; k0 < D_N; k0 += 64) {
        const size_t poff = (size_t)(k0 >> 6) * 8192;   // panel p*2 stride
        __syncthreads();
        #pragma unroll
        for (int h = 0; h < 2; ++h) {
            #pragma unroll
            for (int wt = 0; wt < 3; ++wt)
                GLD16(rp[wt] + poff + (h * 256 + wv * 64) * 8,
                      &As[wt][(h * 256 + wv * 64) * 8]);
        }
        if (wv < 3) {
            GLD16(bp[0] + k0, &Bs[(wv * 64) * 8]);
            GLD16(bp[1] + k0, &Bs[(192 + wv * 64) * 8]);
        }
        __syncthreads();   // compiler drains vmcnt(0) here -> DMA complete

        #pragma unroll
        for (int kk = 0; kk < 2; ++kk) {
            const int kc = kk * 4 + q;
            bf16x8 bfr[3];
            #pragma unroll
            for (int nt = 0; nt < 3; ++nt)
                bfr[nt] = *reinterpret_cast<const bf16x8*>(
                    &Bs[(kc * 48 + nt * 16 + l15) * 8]);
            #pragma unroll
            for (int wt = 0; wt < 3; ++wt) {
                bf16x8 afr = *reinterpret_cast<const bf16x8*>(
                    &As[wt][(kc * 64 + wv * 16 + l15) * 8]);
                #pragma unroll
                for (int nt = 0; nt < 3; ++nt)
                    acc[wt][nt] = __builtin_amdgcn_mfma_f32_16x16x32_bf16(
                        afr, bfr[nt], acc[wt][nt], 0, 0, 0);
            }
        }
    }

    // epilogue: out row = mh*64 + wv*16 + q*4 + r, col = token colL+nt*16+l15
    const int mrow = mh * 64 + wv * 16 + q * 4;
    #pragma unroll
    for (int nt = 0; nt < 3; ++nt) {
        const int token = colL + nt * 16 + l15;
        f32x4 aq = acc[0][nt] * INV_TEMP;
        short4 s4;
        s4.x = f2bf(aq[0]); s4.y = f2bf(aq[1]); s4.z = f2bf(aq[2]); s4.w = f2bf(aq[3]);
        *reinterpret_cast<short4*>(Yq + ((size_t)b * Ltok + token) * 128 + mrow) = s4;
        f32x4 ak = acc[1][nt];
        s4.x = f2bf(ak[0]); s4.y = f2bf(ak[1]); s4.z = f2bf(ak[2]); s4.w = f2bf(ak[3]);
        *reinterpret_cast<short4*>(Yk + ((size_t)b * Ltok + token) * 128 + mrow) = s4;
        #pragma unroll
        for (int rr = 0; rr < 4; ++rr)
            Yv[((size_t)b * FF_N + mrow + rr) * Ltok + token] = f2bf(acc[2][nt][rr]);
    }
}

// ---------------- demo attention, single-pass bf16 MFMA -------------------
// Block = (b, n, ti, i-half). 192 threads = 3 waves; wave w -> i-tile w of the
// 48-row half. Q/K/V fragments loaded DIRECT from global (token-major dk/dq,
// channel-major dv). Scores for all j (<= 21 tiles, templated) in registers;
// single-pass softmax; one LDS buffer (Pt) + one barrier; PV direct-V.
template<int NT>
__device__ __forceinline__ void demo_core(
    const short* __restrict__ dqS, const short* __restrict__ dkS,
    const short* __restrict__ dvS, short* __restrict__ dvaS,
    short* __restrict__ Pt, int b, int n, int ti, int ih)
{
    constexpr int NTP = (NT + 1) & ~1;        // k-padded tile count for PV
    const int tid = threadIdx.x;
    const int lane = tid & 63, w = tid >> 6;  // w in 0..2
    const int l15 = lane & 15, q = lane >> 4;
    const int jmax = (ti + 1) * 84;

    // QK: A-frag rows i from dk (clamp out-of-frame rows -> finite scores)
    const int irow = ih * 48 + w * 16 + l15;
    const int tokA = ti * 84 + (irow < 84 ? irow : 83);
    bf16x8 afr = *reinterpret_cast<const bf16x8*>(
        dkS + ((size_t)b * DI_N + tokA) * 128 + n * 32 + q * 8);

    f32x4 s[NT];
    #pragma unroll
    for (int nt = 0; nt < NT; ++nt) {
        bf16x8 bfr = *reinterpret_cast<const bf16x8*>(
            dqS + ((size_t)b * DI_N + nt * 16 + l15) * 128 + n * 32 + q * 8);
        f32x4 z = {};
        s[nt] = __builtin_amdgcn_mfma_f32_16x16x32_bf16(afr, bfr, z, 0, 0, 0);
    }

    // softmax over j per row r (rows i = base + q*4 + r, cols l15 within tile)
    const int mstart = jmax - (NT - 1) * 16;  // mask l15 >= mstart in last tile
    #pragma unroll
    for (int r = 0; r < 4; ++r) {
        if (l15 >= mstart) s[NT - 1][r] = -3.0e38f;
        float mx = s[0][r];
        #pragma unroll
        for (int nt = 1; nt < NT; ++nt) mx = fmaxf(mx, s[nt][r]);
        #pragma unroll
        for (int o = 1; o < 16; o <<= 1) mx = fmaxf(mx, __shfl_xor(mx, o));
        float sm = 0.f;
        #pragma unroll
        for (int nt = 0; nt < NT; ++nt) {
            float e = __expf(s[nt][r] - mx);
            s[nt][r] = e; sm += e;
        }
        #pragma unroll
        for (int o = 1; o < 16; o <<= 1) sm += __shfl_xor(sm, o);
        float inv = 1.f / sm;
        #pragma unroll
        for (int nt = 0; nt < NT; ++nt) s[nt][r] *= inv;
    }

    // write normalized P to Pt[i_local][j] (stride 360 -> 2-way-free banks)
    #pragma unroll
    for (int nt = 0; nt < NT; ++nt)
        #pragma unroll
        for (int r = 0; r < 4; ++r)
            Pt[(w * 16 + q * 4 + r) * 360 + nt * 16 + l15] = f2bf(s[nt][r]);
    if (NTP != NT) {   // zero k-pad tile
        #pragma unroll
        for (int r = 0; r < 4; ++r)
            Pt[(w * 16 + q * 4 + r) * 360 + NT * 16 + l15] = 0;
    }
    __syncthreads();

    // PV: wave w -> n-tile it=w (its own 16 i-cols), ct in {0,1} (c-tiles)
    f32x4 oacc[2] = {};
    #pragma unroll
    for (int kk = 0; kk < NTP / 2; ++kk) {
        bf16x8 pb = *reinterpret_cast<const bf16x8*>(
            &Pt[(w * 16 + l15) * 360 + kk * 32 + q * 8]);
        #pragma unroll
        for (int ct = 0; ct < 2; ++ct) {
            bf16x8 va = *reinterpret_cast<const bf16x8*>(
                dvS + ((size_t)b * FF_N + n * 32 + ct * 16 + l15) * DI_N + kk * 32 + q * 8);
            oacc[ct] = __builtin_amdgcn_mfma_f32_16x16x32_bf16(va, pb, oacc[ct], 0, 0, 0);
        }
    }

    // epilogue: c = ct*16 + q*4 + r, i = ih*48 + w*16 + l15
    const int ig = ih * 48 + w * 16 + l15;
    if (ig < 84) {
        #pragma unroll
        for (int ct = 0; ct < 2; ++ct)
            #pragma unroll
            for (int r = 0; r < 4; ++r)
                dvaS[((size_t)b * FF_N + n * 32 + ct * 16 + q * 4 + r) * DI_N + ti * 84 + ig] =
                    f2bf(oacc[ct][r]);
    }
}

__global__ __launch_bounds__(192) void demo_attn_mfma_kernel(const short* __restrict__ ws)
{
    __shared__ short Pt[48 * 360];   // 34.56 KB

    const short* dqS = ws + S_DQ;
    const short* dkS = ws + S_DK;
    const short* dvS = ws + S_DV;
    short* dvaS = const_cast<short*>(ws) + S_DVA;

    const int bid = blockIdx.x;      // ((b*4 + n)*4 + ti)*2 + ih
    const int ih = bid & 1, ti = (bid >> 1) & 3;
    const int n = (bid >> 3) & 3, b = bid >> 5;

    switch (ti) {
        case 0: demo_core<6>(dqS, dkS, dvS, dvaS, Pt, b, n, ti, ih); break;
        case 1: demo_core<11>(dqS, dkS, dvS, dvaS, Pt, b, n, ti, ih); break;
        case 2: demo_core<16>(dqS, dkS, dvS, dvaS, Pt, b, n, ti, ih); break;
        default: demo_core<21>(dqS, dkS, dvS, dvaS, Pt, b, n, ti, ih); break;
    }
}

// ---------------- obs attention, bf16 MFMA ----------------
__global__ __launch_bounds__(256, 4) void obs_attn_mfma_kernel(const short* __restrict__ ws)
{
    __shared__ short Qt[96 * 40];
    __shared__ short Kt[64 * 40];
    __shared__ short Vs[32 * 72];
    __shared__ short Pt[96 * 72];

    const short* dkS = ws + S_DK;
    const short* dvaS = ws + S_DVA;
    const short* oqS = ws + S_OQ;
    const short* okS = ws + S_OK;
    const short* ovS = ws + S_OV;
    short* ovaS = const_cast<short*>(ws) + S_OVA;

    const int bid = blockIdx.x;
    const int b = bid >> 7, rem = bid & 127, t = rem >> 2, n = rem & 3;

    const int tid = threadIdx.x;
    const int lane = tid & 63, wv = tid >> 6;
    const int l15 = lane & 15, q = lane >> 4;

    for (int l = tid; l < 384; l += 256) {
        int i = l >> 2, c0 = (l & 3) * 8;
        bf16x8 pk = {0,0,0,0,0,0,0,0};
        if (i < HW_N)
            pk = *reinterpret_cast<const bf16x8*>(
                oqS + ((size_t)b * OI_N + t * 84 + i) * 128 + n * 32 + c0);
        *reinterpret_cast<bf16x8*>(&Qt[i * 40 + c0]) = pk;
    }

    const int pv_mt = wv & 1;
    const int pv_nb = wv >> 1;
    f32x4 oacc[3] = {};

    for (int jc = 0; jc < 448; jc += 64) {
        __syncthreads();
        {
            int jl = tid >> 2, c0 = (tid & 3) * 8;
            int jg = jc + jl;
            bf16x8 pk = {0,0,0,0,0,0,0,0};
            if (jg < DI_N)
                pk = *reinterpret_cast<const bf16x8*>(
                    dkS + ((size_t)b * DI_N + jg) * 128 + n * 32 + c0);
            else if (jg < CAT_N)
                pk = *reinterpret_cast<const bf16x8*>(
                    okS + ((size_t)b * OI_N + t * 84 + (jg - DI_N)) * 128 + n * 32 + c0);
            *reinterpret_cast<bf16x8*>(&Kt[jl * 40 + c0]) = pk;
        }
        {
            int c = tid >> 3, j0 = (tid & 7) * 8;
            int jg0 = jc + j0;
            const short* dvaRow = dvaS + ((size_t)b * FF_N + n * 32 + c) * DI_N;
            const short* ovRow = ovS + ((size_t)b * FF_N + n * 32 + c) * OI_N + t * 84;
            bf16x8 pk;
            if (jg0 + 8 <= DI_N) {
                pk = *reinterpret_cast<const bf16x8*>(dvaRow + jg0);
            } else if (jg0 >= DI_N && jg0 + 8 <= CAT_N) {
                short4 lo = *reinterpret_cast<const short4*>(ovRow + (jg0 - DI_N));
                short4 hi = *reinterpret_cast<const short4*>(ovRow + (jg0 - DI_N) + 4);
                pk[0]=lo.x; pk[1]=lo.y; pk[2]=lo.z; pk[3]=lo.w;
                pk[4]=hi.x; pk[5]=hi.y; pk[6]=hi.z; pk[7]=hi.w;
            } else {
                #pragma unroll
                for (int p = 0; p < 8; ++p) {
                    int jg = jg0 + p;
                    pk[p] = (jg < DI_N) ? dvaRow[jg]
                          : ((jg < CAT_N) ? ovRow[jg - DI_N] : (short)0);
                }
            }
            *reinterpret_cast<bf16x8*>(&Vs[c * 72 + j0]) = pk;
        }
        __syncthreads();

        f32x4 s[6];
        bf16x8 afr = *reinterpret_cast<const bf16x8*>(&Kt[(wv * 16 + l15) * 40 + q * 8]);
        #pragma unroll
        for (int nt = 0; nt < 6; ++nt) {
            bf16x8 bfr = *reinterpret_cast<const bf16x8*>(&Qt[(nt * 16 + l15) * 40 + q * 8]);
            f32x4 z = {};
            s[nt] = __builtin_amdgcn_mfma_f32_16x16x32_bf16(afr, bfr, z, 0, 0, 0);
        }
        float inv[4];
        #pragma unroll
        for (int r = 0; r < 4; ++r) {
            if (l15 >= 4) s[5][r] = -3.0e38f;
            float m2 = s[0][r];
            #pragma unroll
            for (int nt2 = 1; nt2 < 6; ++nt2) m2 = fmaxf(m2, s[nt2][r]);
            #pragma unroll
            for (int o = 1; o < 16; o <<= 1) m2 = fmaxf(m2, __shfl_xor(m2, o));
            float sm = 0.f;
            #pragma unroll
            for (int nt2 = 0; nt2 < 6; ++nt2) { float e = __expf(s[nt2][r] - m2); s[nt2][r] = e; sm += e; }
            #pragma unroll
            for (int o = 1; o < 16; o <<= 1) sm += __shfl_xor(sm, o);
            inv[r] = 1.f / sm;
        }
        #pragma unroll
        for (int nt = 0; nt < 6; ++nt) {
            short4 pk4;
            pk4.x = f2bf(s[nt][0] * inv[0]);
            pk4.y = f2bf(s[nt][1] * inv[1]);
            pk4.z = f2bf(s[nt][2] * inv[2]);
            pk4.w = f2bf(s[nt][3] * inv[3]);
            *reinterpret_cast<short4*>(&Pt[(nt * 16 + l15) * 72 + wv * 16 + q * 4]) = pk4;
        }
        __syncthreads();

        #pragma unroll
        for (int kk = 0; kk < 2; ++kk) {
            bf16x8 va = *reinterpret_cast<const bf16x8*>(&Vs[(pv_mt * 16 + l15) * 72 + kk * 32 + q * 8]);
            #pragma unroll
            for (int u = 0; u < 3; ++u) {
                int nt = pv_nb + u * 2;
                bf16x8 pb = *reinterpret_cast<const bf16x8*>(&Pt[(nt * 16 + l15) * 72 + kk * 32 + q * 8]);
                oacc[u] = __builtin_amdgcn_mfma_f32_16x16x32_bf16(va, pb, oacc[u], 0, 0, 0);
            }
        }
    }

    #pragma unroll
    for (int u = 0; u < 3; ++u) {
        int i = (pv_nb + u * 2) * 16 + l15;
        if (i < HW_N) {
            short4 st;
            st.x = f2bf(oacc[u][0]); st.y = f2bf(oacc[u][1]);
            st.z = f2bf(oacc[u][2]); st.w = f2bf(oacc[u][3]);
            *reinterpret_cast<short4*>(
                ovaS + (((size_t)b * OT_N + t) * 84 + i) * 128 + n * 32 + pv_mt * 16 + q * 4) = st;
        }
    }
}

// ---------------- output projection + ReLU + residual (bf16 x) + stats ----
// Wave-autonomous: each wave owns 32 output channels (full K=128 of Wo held
// in 32 VGPRs, loaded once from L2) and streams 48 tokens (3 n-tiles) with
// B-fragments loaded DIRECT from global ova (token-major -> coalesced
// 16B/lane). No LDS staging, no barriers in the compute loop.
__global__ __launch_bounds__(256) void outproj_mfma_kernel(
    short* __restrict__ xbf, const short* __restrict__ ws, int layer,
    float* __restrict__ stats)
{
    __shared__ float redS[4][32];
    __shared__ float redQ[4][32];

    const int bid = blockIdx.x;
    const int t8 = bid & 7;           // XCD id (round-robin dispatch)
    const int rr = bid >> 3;
    const int c32 = rr & 15;          // channel block: 32 chans
    const int tc = rr >> 4;           // 0..13
    const int tchunk = tc * 8 + t8;   // 0..111, 192 tokens each
    const int o0 = c32 * 32;

    const int tid = threadIdx.x;
    const int lane = tid & 63, wv = tid >> 6;
    const int l15 = lane & 15, q = lane >> 4;

    // this wave's 48 tokens (global flat token id over [B][2688])
    const int g0 = tchunk * 192 + wv * 48;
    const int b = g0 / OI_N;                    // 2688 % 192 == 0 -> constant
    const size_t xbase = (size_t)(g0 + DI_N * (b + 1)) * 512 + o0;

    const short* Wo = ws + SW_OWO + layer * 65536;
    const short* ova = ws + S_OVA;

    // weights in registers: afr[mtile][kchunk], row m = o0+mt*16+l15,
    // k elements kc*32 + q*8 .. +8 (matches 16x16x32 A-frag layout)
    bf16x8 afr[2][4];
    #pragma unroll
    for (int mt = 0; mt < 2; ++mt)
        #pragma unroll
        for (int kc = 0; kc < 4; ++kc)
            afr[mt][kc] = *reinterpret_cast<const bf16x8*>(
                Wo + (size_t)(o0 + mt * 16 + l15) * FF_N + kc * 32 + q * 8);

    float csum[2][4] = {}, csq[2][4] = {};

    #pragma unroll
    for (int nt = 0; nt < 3; ++nt) {
        const int g = g0 + nt * 16;
        // B-frag direct from global: row n = token g+l15, k = kc*32 + q*8
        const short* ovaT = ova + (size_t)(g + l15) * FF_N + q * 8;
        bf16x8 bfr[4];
        #pragma unroll
        for (int kc = 0; kc < 4; ++kc)
            bfr[kc] = *reinterpret_cast<const bf16x8*>(ovaT + kc * 32);

        f32x4 acc[2] = {};
        #pragma unroll
        for (int kc = 0; kc < 4; ++kc) {
            acc[0] = __builtin_amdgcn_mfma_f32_16x16x32_bf16(afr[0][kc], bfr[kc], acc[0], 0, 0, 0);
            acc[1] = __builtin_amdgcn_mfma_f32_16x16x32_bf16(afr[1][kc], bfr[kc], acc[1], 0, 0, 0);
        }

        // RMW x: token = g+l15 (acc col), chans o0+mt*16+q*4..+3 (acc rows)
        #pragma unroll
        for (int mt = 0; mt < 2; ++mt) {
            short* p = xbf + xbase + (size_t)(nt * 16 + l15) * 512 + mt * 16 + q * 4;
            short4 old4 = *reinterpret_cast<short4*>(p);
            float ov[4] = {bf2f(old4.x), bf2f(old4.y), bf2f(old4.z), bf2f(old4.w)};
            short4 nw;
            short* nwp = &nw.x;
            #pragma unroll
            for (int r = 0; r < 4; ++r) {
                float v = acc[mt][r];
                float y = ov[r] + (v > 0.f ? v : 0.f);
                short ybf = f2bf(y);
                nwp[r] = ybf;
                float yr = bf2f(ybf);
                csum[mt][r] += yr;
                csq[mt][r] += yr * yr;
            }
            *reinterpret_cast<short4*>(p) = nw;
        }
    }

    // stats: reduce over the 16 token-lanes, then across the 4 waves via LDS
    #pragma unroll
    for (int mt = 0; mt < 2; ++mt) {
        #pragma unroll
        for (int r = 0; r < 4; ++r) {
            float s = csum[mt][r], qq = csq[mt][r];
            #pragma unroll
            for (int o = 1; o < 16; o <<= 1) {
                s += __shfl_xor(s, o);
                qq += __shfl_xor(qq, o);
            }
            if (l15 == 0) {
                redS[wv][mt * 16 + q * 4 + r] = s;
                redQ[wv][mt * 16 + q * 4 + r] = qq;
            }
        }
    }
    __syncthreads();
    if (tid < 32) {
        float s = redS[0][tid] + redS[1][tid] + redS[2][tid] + redS[3][tid];
        float qq = redQ[0][tid] + redQ[1][tid] + redQ[2][tid] + redQ[3][tid];
        atomicAdd(&stats[o0 + tid], s);
        atomicAdd(&stats[512 + o0 + tid], qq);
    }
}

// ---------------- BN in place on bf16 xbf + demo-stats for next layer -----
__global__ __launch_bounds__(256) void bn_mid_kernel(
    short* __restrict__ xbf, const float* __restrict__ stats,
    const float* __restrict__ gamma, const float* __restrict__ beta,
    float* __restrict__ stats_next)
{
    __shared__ float red_s[4][512];
    __shared__ float red_q[4][512];

    const int bid = blockIdx.x;
    const int b = bid / 63, tt = bid % 63;
    const int t0 = tt * 48;
    const bool is_demo = (tt < 7);
    const int tid = threadIdx.x;
    const int chg = tid & 63;
    const int trow = tid >> 6;

    float mean[8], rs[8], g[8], bb[8];
    #pragma unroll
    for (int j = 0; j < 8; ++j) {
        int c = chg * 8 + j;
        float m = stats[c] * INV_CNT;
        float var = stats[512 + c] * INV_CNT - m * m;
        mean[j] = m;
        rs[j] = rsqrtf(var + BN_EPS);
        g[j] = gamma[c];
        bb[j] = beta[c];
    }

    float psum[8] = {}, psq[8] = {};
    #pragma unroll
    for (int it = 0; it < 12; ++it) {
        int tok = t0 + it * 4 + trow;
        short* p = xbf + ((size_t)b * THW_N + tok) * 512 + chg * 8;
        bf16x8 v = *reinterpret_cast<bf16x8*>(p);
        bf16x8 w;
        #pragma unroll
        for (int j = 0; j < 8; ++j) {
            float y = g[j] * (bf2f(v[j]) - mean[j]) * rs[j] + bb[j];
            short yb = f2bf(y);
            w[j] = yb;
            if (is_demo) {
                float yr = bf2f(yb);
                psum[j] += yr; psq[j] += yr * yr;
            }
        }
        *reinterpret_cast<bf16x8*>(p) = w;
    }
    if (!is_demo) return;
    #pragma unroll
    for (int j = 0; j < 8; ++j) {
        red_s[trow][chg * 8 + j] = psum[j];
        red_q[trow][chg * 8 + j] = psq[j];
    }
    __syncthreads();
    #pragma unroll
    for (int h = 0; h < 2; ++h) {
        int c = tid + h * 256;
        float s = red_s[0][c] + red_s[1][c] + red_s[2][c] + red_s[3][c];
        float qq = red_q[0][c] + red_q[1][c] + red_q[2][c] + red_q[3][c];
        atomicAdd(&stats_next[c], s);
        atomicAdd(&stats_next[512 + c], qq);
    }
}

// ---------------- final BN -> fp32 channel-major d_out --------------------
__global__ __launch_bounds__(256) void bn_out_kernel(
    const short* __restrict__ xbf, float* __restrict__ out_f,
    const float* __restrict__ stats,
    const float* __restrict__ gamma, const float* __restrict__ beta)
{
    __shared__ float tile[48][65];

    const int bid = blockIdx.x;
    const int b = bid / 504, rem = bid % 504, tt = rem >> 3, cblk = rem & 7;
    const int t0 = tt * 48, c0 = cblk * 64;
    const int tid = threadIdx.x;
    const int cg = tid & 15;

    float mean[4], rs[4], g[4], bb[4];
    #pragma unroll
    for (int j = 0; j < 4; ++j) {
        int c = c0 + cg * 4 + j;
        float m = stats[c] * INV_CNT;
        float var = stats[512 + c] * INV_CNT - m * m;
        mean[j] = m; rs[j] = rsqrtf(var + BN_EPS);
        g[j] = gamma[c]; bb[j] = beta[c];
    }

    #pragma unroll
    for (int l0 = 0; l0 < 768; l0 += 256) {
        int l = l0 + tid;
        int tok = l >> 4;
        short4 v = *reinterpret_cast<const short4*>(
            xbf + ((size_t)b * THW_N + t0 + tok) * 512 + c0 + cg * 4);
        tile[tok][cg * 4 + 0] = g[0] * (bf2f(v.x) - mean[0]) * rs[0] + bb[0];
        tile[tok][cg * 4 + 1] = g[1] * (bf2f(v.y) - mean[1]) * rs[1] + bb[1];
        tile[tok][cg * 4 + 2] = g[2] * (bf2f(v.z) - mean[2]) * rs[2] + bb[2];
        tile[tok][cg * 4 + 3] = g[3] * (bf2f(v.w) - mean[3]) * rs[3] + bb[3];
    }
    __syncthreads();
    #pragma unroll
    for (int l0 = 0; l0 < 768; l0 += 256) {
        int l = l0 + tid;
        int cc = l / 12, tg = l % 12;
        float4 o;
        o.x = tile[tg * 4 + 0][cc];
        o.y = tile[tg * 4 + 1][cc];
        o.z = tile[tg * 4 + 2][cc];
        o.w = tile[tg * 4 + 3][cc];
        *reinterpret_cast<float4*>(
            out_f + ((size_t)b * D_N + c0 + cc) * THW_N + t0 + tg * 4) = o;
    }
}

// ---------------- launch ----------------
extern "C" void kernel_launch(void* const* d_in, const int* in_sizes, int n_in,
                              void* d_out, int out_size, void* d_ws, size_t ws_size,
                              hipStream_t stream)
{
    const float* inp  = (const float*)d_in[0];
    const float* dwq  = (const float*)d_in[1];
    const float* dwk  = (const float*)d_in[2];
    const float* dwv  = (const float*)d_in[3];
    const float* owq  = (const float*)d_in[5];
    const float* owk  = (const float*)d_in[6];
    const float* owv  = (const float*)d_in[7];
    const float* owo  = (const float*)d_in[8];
    const float* gam  = (const float*)d_in[9];
    const float* bet  = (const float*)d_in[10];
    float* x  = (float*)d_out;
    float* stats = (float*)d_ws;          // [2][1024]
    short* wsS = (short*)(stats + 2048);
    short* xbf = wsS + S_XBF;

    cvt_w_kernel<<<448, 256, 0, stream>>>(dwq, dwk, dwv, owq, owk, owv, owo, wsS, stats);
    xin_kernel<<<4032, 256, 0, stream>>>(inp, xbf, stats);

    for (int layer = 0; layer < 2; ++layer) {
        float* stL = stats + layer * 1024;
        size_t coff = (size_t)layer * D_N;
        proj_mfma_kernel<<<1008, 256, 0, stream>>>(xbf, wsS, layer);
        demo_attn_mfma_kernel<<<256, 192, 0, stream>>>(wsS);
        obs_attn_mfma_kernel<<<1024, 256, 0, stream>>>(wsS);
        outproj_mfma_kernel<<<1792, 256, 0, stream>>>(xbf, wsS, layer, stL);
        if (layer == 0) {
            bn_mid_kernel<<<504, 256, 0, stream>>>(
                xbf, stL, gam + coff, bet + coff, stats + 1024);
        } else {
            bn_out_kernel<<<4032, 256, 0, stream>>>(
                xbf, x, stL, gam + coff, bet + coff);
        }
    }
    (void)in_sizes; (void)n_in; (void)out_size; (void)ws_size;
}

// Round 5
// 305.056 us; speedup vs baseline: 1.4928x; 1.0284x over previous
//
#include <hip/hip_runtime.h>

// ---------------- problem constants ----------------
#define B_N 8
#define D_N 512
#define T_N 36
#define HW_N 84
#define THW_N 3024
#define DT_N 4
#define OT_N 32
#define NH_N 4
#define FF_N 128
#define CH_N 32
#define DI_N 336      // demo tokens 4*84
#define OI_N 2688     // obs tokens 32*84
#define CAT_N 420
#define INV_TEMP 0.04419417382415922f   // 1/sqrt(512)
#define BN_EPS 1e-5f
#define INV_CNT (1.0f / 24192.0f)       // 1/(B*THW)

// workspace: float stats[2][1024] at base (sum[512], sumsq[512] per layer),
// then bf16 (short) arena at +8192B.
#define SW_DWQ 0
#define SW_DWK 131072
#define SW_DWV 262144
#define SW_OWQ 393216
#define SW_OWK 524288
#define SW_OWV 655360
#define SW_OWO 786432
#define S_DQ   917504     // [b][336][128] token-major (INV_TEMP folded)
#define S_DK   1261568    // [b][336][128] token-major
#define S_DV   1605632    // [b][128][336] channel-major
#define S_DVA  1949696    // [b][128][336] channel-major
#define S_OQ   2293760    // [b][2688][128] token-major (INV_TEMP folded)
#define S_OK   5046272    // [b][2688][128] token-major
#define S_OV   7798784    // [b][128][2688] channel-major
#define S_OVA  10551296   // [b][32][84][128] token-major
#define S_XBF  13303808   // [b][3024][512] token-major bf16 x

typedef short bf16x8 __attribute__((ext_vector_type(8)));   // 8 bf16 in 4 VGPRs
typedef float f32x4 __attribute__((ext_vector_type(4)));
typedef unsigned int u32;

// 16B global->LDS DMA: per-lane global src, wave-uniform LDS base (+lane*16)
#define GLD16(SRC, DST) __builtin_amdgcn_global_load_lds( \
    (const __attribute__((address_space(1))) u32*)(SRC), \
    (__attribute__((address_space(3))) u32*)(DST), 16, 0, 0)

__device__ __forceinline__ short f2bf(float f) {
    unsigned u = __float_as_uint(f);
    u += 0x7fffu + ((u >> 16) & 1u);          // round-to-nearest-even
    return (short)(u >> 16);
}
__device__ __forceinline__ float bf2f(short s) {
    return __uint_as_float(((unsigned)(unsigned short)s) << 16);
}

// ---------------- weight conversion + stats zero (once per launch) --------
// QKV weights (a<6) are stored in proj's LDS-staging order so the DMA source
// is CONTIGUOUS (base + lane*16): [layer][panel p*2+mh][kc<8][m<64][8bf16],
// p = k/64 (K-panel), mh = M-half, kc = (k/8)%8, m = row%64.
// owo (a==6) stays row-major [layer][512][128] for outproj fragments.
__global__ __launch_bounds__(256) void cvt_w_kernel(
    const float* __restrict__ s0, const float* __restrict__ s1,
    const float* __restrict__ s2, const float* __restrict__ s3,
    const float* __restrict__ s4, const float* __restrict__ s5,
    const float* __restrict__ s6, short* __restrict__ dst,
    float* __restrict__ stats)
{
    const int bid = blockIdx.x;
    if (bid == 0) {   // zero both layers' stats accumulators (2048 floats)
        #pragma unroll
        for (int k = 0; k < 8; ++k) stats[threadIdx.x * 8 + k] = 0.f;
    }
    const int a = bid >> 6, blk = bid & 63;
    const float* src;
    switch (a) {
        case 0: src = s0; break; case 1: src = s1; break;
        case 2: src = s2; break; case 3: src = s3; break;
        case 4: src = s4; break; case 5: src = s5; break;
        default: src = s6;
    }
    const int idx = (blk * 256 + (int)threadIdx.x) * 8;
    float4 f0 = *reinterpret_cast<const float4*>(src + idx);
    float4 f1 = *reinterpret_cast<const float4*>(src + idx + 4);
    bf16x8 pk;
    pk[0] = f2bf(f0.x); pk[1] = f2bf(f0.y); pk[2] = f2bf(f0.z); pk[3] = f2bf(f0.w);
    pk[4] = f2bf(f1.x); pk[5] = f2bf(f1.y); pk[6] = f2bf(f1.z); pk[7] = f2bf(f1.w);
    size_t dstoff;
    if (a < 6) {
        const int layer = idx >> 16;
        const int w = idx & 65535;
        const int mg = w >> 9;           // row 0..127
        const int k  = w & 511;          // col (chunk-aligned, k%8==0)
        const int p  = k >> 6;           // K-panel 0..7
        const int kc = (k >> 3) & 7;     // chunk-in-panel 0..7
        const int mh = mg >> 6;          // M-half
        const int m  = mg & 63;
        dstoff = (size_t)layer * 65536 +
                 (size_t)(((p * 2 + mh) * 8 + kc) * 64 + m) * 8;
    } else {
        dstoff = idx;
    }
    *reinterpret_cast<bf16x8*>(dst + (size_t)a * 131072 + dstoff) = pk;
}

// ---------------- input staging: fp32 ch-major -> bf16 token-major -------
__global__ __launch_bounds__(256) void xin_kernel(
    const float* __restrict__ in_f, short* __restrict__ xbf,
    float* __restrict__ stats0)
{
    __shared__ short tile[48][65];
    __shared__ float red_s[16][64];
    __shared__ float red_q[16][64];

    const int bid = blockIdx.x;
    const int b = bid / 504, rem = bid % 504, tt = rem >> 3, cblk = rem & 7;
    const int t0 = tt * 48, c0 = cblk * 64;
    const int tid = threadIdx.x;
    const bool is_demo = (tt < 7);

    #pragma unroll
    for (int l0 = 0; l0 < 768; l0 += 256) {
        int l = l0 + tid;
        int cc = l / 12, tg = l % 12;
        size_t addr = ((size_t)b * D_N + c0 + cc) * THW_N + t0 + tg * 4;
        float4 v = *reinterpret_cast<const float4*>(in_f + addr);
        tile[tg * 4 + 0][cc] = f2bf(v.x);
        tile[tg * 4 + 1][cc] = f2bf(v.y);
        tile[tg * 4 + 2][cc] = f2bf(v.z);
        tile[tg * 4 + 3][cc] = f2bf(v.w);
    }
    __syncthreads();
    float psum[4] = {}, psq[4] = {};
    const int cg = tid & 15;
    #pragma unroll
    for (int l0 = 0; l0 < 768; l0 += 256) {
        int l = l0 + tid;
        int tk = l >> 4;
        short4 s4;
        s4.x = tile[tk][cg * 4 + 0];
        s4.y = tile[tk][cg * 4 + 1];
        s4.z = tile[tk][cg * 4 + 2];
        s4.w = tile[tk][cg * 4 + 3];
        *reinterpret_cast<short4*>(
            xbf + ((size_t)b * THW_N + t0 + tk) * 512 + c0 + cg * 4) = s4;
        if (is_demo) {
            float v0 = bf2f(s4.x), v1 = bf2f(s4.y), v2 = bf2f(s4.z), v3 = bf2f(s4.w);
            psum[0] += v0; psum[1] += v1; psum[2] += v2; psum[3] += v3;
            psq[0] += v0 * v0; psq[1] += v1 * v1; psq[2] += v2 * v2; psq[3] += v3 * v3;
        }
    }
    if (!is_demo) return;
    __syncthreads();
    #pragma unroll
    for (int j = 0; j < 4; ++j) {
        red_s[tid >> 4][cg * 4 + j] = psum[j];
        red_q[tid >> 4][cg * 4 + j] = psq[j];
    }
    __syncthreads();
    if (tid < 64) {
        float s = 0.f, q = 0.f;
        #pragma unroll
        for (int r = 0; r < 16; ++r) { s += red_s[r][tid]; q += red_q[r][tid]; }
        atomicAdd(&stats0[c0 + tid], s);
        atomicAdd(&stats0[512 + c0 + tid], q);
    }
}

// ---------------- fused QKV projection, LDS-staged async bf16 MFMA --------
// Block = (b, ct token-tile of 48, mh M-half of 64 rows); 4 waves. Weights
// pre-permuted by cvt_w into the exact LDS chunk order, so each GLD16 streams
// 1KB CONTIGUOUS global bytes (base + lane*16) -> minimal L2 transactions.
// BK=64 -> 8 K-steps. LDS 30KB; grid 1008 ~= 4 blocks/CU.
__global__ __launch_bounds__(256) void proj_mfma_kernel(
    const short* __restrict__ xbf, short* __restrict__ ws, int layer)
{
    __shared__ short As[3][4096];   // per wt: chunk (kc*64+m) of 8 shorts, kc<8,m<64
    __shared__ short Bs[3072];      // chunk (kc*48+n), kc<8, n<48

    const int tid = threadIdx.x;
    const int lane = tid & 63, wv = tid >> 6;
    const int l15 = lane & 15, q = lane >> 4;

    const int bid = blockIdx.x;
    const int mh = bid & 1;
    const int rem = bid >> 1;
    const int b = rem / 63, ct = rem - b * 63;
    const bool is_demo = (ct < 7);
    const int woff = layer * 65536;
    const short* W0 = ws + (is_demo ? SW_DWQ : SW_OWQ) + woff;
    const short* W1 = ws + (is_demo ? SW_DWK : SW_OWK) + woff;
    const short* W2 = ws + (is_demo ? SW_DWV : SW_OWV) + woff;
    const int Ltok = is_demo ? DI_N : OI_N;
    const int colL = is_demo ? ct * 48 : (ct - 7) * 48;
    short* Yq = ws + (is_demo ? S_DQ : S_OQ);
    short* Yk = ws + (is_demo ? S_DK : S_OK);
    short* Yv = ws + (is_demo ? S_DV : S_OV);
    const short* Xb = xbf + ((size_t)b * THW_N + (is_demo ? 0 : DI_N) + colL) * 512;

    // staged-weight DMA source: panel (p*2+mh) of 4096 shorts; chunk within
    // panel = h*256 + wv*64 + lane  (lane*16B contiguous).
    const short* rp[3];
    rp[0] = W0 + (size_t)mh * 4096 + lane * 8;
    rp[1] = W1 + (size_t)mh * 4096 + lane * 8;
    rp[2] = W2 + (size_t)mh * 4096 + lane * 8;
    // Bs chunk c = h*192 + wv*64 + lane (wv<3) -> kc = c/48, n = c%48.
    const short* bp[2];
    #pragma unroll
    for (int h = 0; h < 2; ++h) {
        int c = h * 192 + wv * 64 + lane;
        bp[h] = Xb + (size_t)(c % 48) * 512 + (c / 48) * 8;
    }

    f32x4 acc[3][3] = {};

    for (int k0 = 0; k0 < D_N; k0 += 64) {
        const size_t poff = (size_t)(k0 >> 6) * 8192;   // panel p*2 stride
        __syncthreads();
        #pragma unroll
        for (int h = 0; h < 2; ++h) {
            #pragma unroll
            for (int wt = 0; wt < 3; ++wt)
                GLD16(rp[wt] + poff + (h * 256 + wv * 64) * 8,
                      &As[wt][(h * 256 + wv * 64) * 8]);
        }
        if (wv < 3) {
            GLD16(bp[0] + k0, &Bs[(wv * 64) * 8]);
            GLD16(bp[1] + k0, &Bs[(192 + wv * 64) * 8]);
        }
        __syncthreads();   // compiler drains vmcnt(0) here -> DMA complete

        #pragma unroll
        for (int kk = 0; kk < 2; ++kk) {
            const int kc = kk * 4 + q;
            bf16x8 bfr[3];
            #pragma unroll
            for (int nt = 0; nt < 3; ++nt)
                bfr[nt] = *reinterpret_cast<const bf16x8*>(
                    &Bs[(kc * 48 + nt * 16 + l15) * 8]);
            #pragma unroll
            for (int wt = 0; wt < 3; ++wt) {
                bf16x8 afr = *reinterpret_cast<const bf16x8*>(
                    &As[wt][(kc * 64 + wv * 16 + l15) * 8]);
                #pragma unroll
                for (int nt = 0; nt < 3; ++nt)
                    acc[wt][nt] = __builtin_amdgcn_mfma_f32_16x16x32_bf16(
                        afr, bfr[nt], acc[wt][nt], 0, 0, 0);
            }
        }
    }

    // epilogue: out row = mh*64 + wv*16 + q*4 + r, col = token colL+nt*16+l15
    const int mrow = mh * 64 + wv * 16 + q * 4;
    #pragma unroll
    for (int nt = 0; nt < 3; ++nt) {
        const int token = colL + nt * 16 + l15;
        f32x4 aq = acc[0][nt] * INV_TEMP;
        short4 s4;
        s4.x = f2bf(aq[0]); s4.y = f2bf(aq[1]); s4.z = f2bf(aq[2]); s4.w = f2bf(aq[3]);
        *reinterpret_cast<short4*>(Yq + ((size_t)b * Ltok + token) * 128 + mrow) = s4;
        f32x4 ak = acc[1][nt];
        s4.x = f2bf(ak[0]); s4.y = f2bf(ak[1]); s4.z = f2bf(ak[2]); s4.w = f2bf(ak[3]);
        *reinterpret_cast<short4*>(Yk + ((size_t)b * Ltok + token) * 128 + mrow) = s4;
        #pragma unroll
        for (int rr = 0; rr < 4; ++rr)
            Yv[((size_t)b * FF_N + mrow + rr) * Ltok + token] = f2bf(acc[2][nt][rr]);
    }
}

// ---------------- demo attention, single-pass bf16 MFMA -------------------
// Block = (b, n, ti, i-half). 192 threads = 3 waves; wave w -> i-tile w of the
// 48-row half. Q/K/V fragments loaded DIRECT from global (token-major dk/dq,
// channel-major dv). Scores for all j (<= 21 tiles, templated) in registers;
// single-pass softmax; one LDS buffer (Pt) + one barrier; PV direct-V.
template<int NT>
__device__ __forceinline__ void demo_core(
    const short* __restrict__ dqS, const short* __restrict__ dkS,
    const short* __restrict__ dvS, short* __restrict__ dvaS,
    short* __restrict__ Pt, int b, int n, int ti, int ih)
{
    constexpr int NTP = (NT + 1) & ~1;        // k-padded tile count for PV
    const int tid = threadIdx.x;
    const int lane = tid & 63, w = tid >> 6;  // w in 0..2
    const int l15 = lane & 15, q = lane >> 4;
    const int jmax = (ti + 1) * 84;

    // QK: A-frag rows i from dk (clamp out-of-frame rows -> finite scores)
    const int irow = ih * 48 + w * 16 + l15;
    const int tokA = ti * 84 + (irow < 84 ? irow : 83);
    bf16x8 afr = *reinterpret_cast<const bf16x8*>(
        dkS + ((size_t)b * DI_N + tokA) * 128 + n * 32 + q * 8);

    f32x4 s[NT];
    #pragma unroll
    for (int nt = 0; nt < NT; ++nt) {
        bf16x8 bfr = *reinterpret_cast<const bf16x8*>(
            dqS + ((size_t)b * DI_N + nt * 16 + l15) * 128 + n * 32 + q * 8);
        f32x4 z = {};
        s[nt] = __builtin_amdgcn_mfma_f32_16x16x32_bf16(afr, bfr, z, 0, 0, 0);
    }

    // softmax over j per row r (rows i = base + q*4 + r, cols l15 within tile)
    const int mstart = jmax - (NT - 1) * 16;  // mask l15 >= mstart in last tile
    #pragma unroll
    for (int r = 0; r < 4; ++r) {
        if (l15 >= mstart) s[NT - 1][r] = -3.0e38f;
        float mx = s[0][r];
        #pragma unroll
        for (int nt = 1; nt < NT; ++nt) mx = fmaxf(mx, s[nt][r]);
        #pragma unroll
        for (int o = 1; o < 16; o <<= 1) mx = fmaxf(mx, __shfl_xor(mx, o));
        float sm = 0.f;
        #pragma unroll
        for (int nt = 0; nt < NT; ++nt) {
            float e = __expf(s[nt][r] - mx);
            s[nt][r] = e; sm += e;
        }
        #pragma unroll
        for (int o = 1; o < 16; o <<= 1) sm += __shfl_xor(sm, o);
        float inv = 1.f / sm;
        #pragma unroll
        for (int nt = 0; nt < NT; ++nt) s[nt][r] *= inv;
    }

    // write normalized P to Pt[i_local][j] (stride 360 -> 2-way-free banks)
    #pragma unroll
    for (int nt = 0; nt < NT; ++nt)
        #pragma unroll
        for (int r = 0; r < 4; ++r)
            Pt[(w * 16 + q * 4 + r) * 360 + nt * 16 + l15] = f2bf(s[nt][r]);
    if (NTP != NT) {   // zero k-pad tile
        #pragma unroll
        for (int r = 0; r < 4; ++r)
            Pt[(w * 16 + q * 4 + r) * 360 + NT * 16 + l15] = 0;
    }
    __syncthreads();

    // PV: wave w -> n-tile it=w (its own 16 i-cols), ct in {0,1} (c-tiles)
    f32x4 oacc[2] = {};
    #pragma unroll
    for (int kk = 0; kk < NTP / 2; ++kk) {
        bf16x8 pb = *reinterpret_cast<const bf16x8*>(
            &Pt[(w * 16 + l15) * 360 + kk * 32 + q * 8]);
        #pragma unroll
        for (int ct = 0; ct < 2; ++ct) {
            bf16x8 va = *reinterpret_cast<const bf16x8*>(
                dvS + ((size_t)b * FF_N + n * 32 + ct * 16 + l15) * DI_N + kk * 32 + q * 8);
            oacc[ct] = __builtin_amdgcn_mfma_f32_16x16x32_bf16(va, pb, oacc[ct], 0, 0, 0);
        }
    }

    // epilogue: c = ct*16 + q*4 + r, i = ih*48 + w*16 + l15
    const int ig = ih * 48 + w * 16 + l15;
    if (ig < 84) {
        #pragma unroll
        for (int ct = 0; ct < 2; ++ct)
            #pragma unroll
            for (int r = 0; r < 4; ++r)
                dvaS[((size_t)b * FF_N + n * 32 + ct * 16 + q * 4 + r) * DI_N + ti * 84 + ig] =
                    f2bf(oacc[ct][r]);
    }
}

__global__ __launch_bounds__(192) void demo_attn_mfma_kernel(const short* __restrict__ ws)
{
    __shared__ short Pt[48 * 360];   // 34.56 KB

    const short* dqS = ws + S_DQ;
    const short* dkS = ws + S_DK;
    const short* dvS = ws + S_DV;
    short* dvaS = const_cast<short*>(ws) + S_DVA;

    const int bid = blockIdx.x;      // ((b*4 + n)*4 + ti)*2 + ih
    const int ih = bid & 1, ti = (bid >> 1) & 3;
    const int n = (bid >> 3) & 3, b = bid >> 5;

    switch (ti) {
        case 0: demo_core<6>(dqS, dkS, dvS, dvaS, Pt, b, n, ti, ih); break;
        case 1: demo_core<11>(dqS, dkS, dvS, dvaS, Pt, b, n, ti, ih); break;
        case 2: demo_core<16>(dqS, dkS, dvS, dvaS, Pt, b, n, ti, ih); break;
        default: demo_core<21>(dqS, dkS, dvS, dvaS, Pt, b, n, ti, ih); break;
    }
}

// ---------------- obs attention, bf16 MFMA, wave-direct -------------------
// Rewrite: K rows and V rows are wave-exclusive and Q is iteration-invariant,
// so all three are loaded DIRECT from global (Q once into registers); the only
// cross-wave exchange is the P transpose, double-buffered in LDS -> exactly
// ONE barrier per iteration (was 3) and zero staging phases. Boundary
// handling: K row clamped to 419 / Q row clamped to 83 (both masked
// downstream); P rows with i>=420 written as zero so unguarded V reads
// (finite in-workspace data) contribute nothing.
__global__ __launch_bounds__(256, 4) void obs_attn_mfma_kernel(const short* __restrict__ ws)
{
    __shared__ short Pt[2][96 * 72];   // 27.6 KB double-buffered transpose

    const short* dkS = ws + S_DK;
    const short* dvaS = ws + S_DVA;
    const short* oqS = ws + S_OQ;
    const short* okS = ws + S_OK;
    const short* ovS = ws + S_OV;
    short* ovaS = const_cast<short*>(ws) + S_OVA;

    const int bid = blockIdx.x;
    const int b = bid >> 7, rem = bid & 127, t = rem >> 2, n = rem & 3;

    const int tid = threadIdx.x;
    const int lane = tid & 63, wv = tid >> 6;
    const int l15 = lane & 15, q = lane >> 4;

    // Q fragments once, direct (j>=84 clamped; masked in softmax)
    bf16x8 bfr[6];
    #pragma unroll
    for (int nt = 0; nt < 6; ++nt) {
        int j = nt * 16 + l15; if (j > 83) j = 83;
        bfr[nt] = *reinterpret_cast<const bf16x8*>(
            oqS + ((size_t)b * OI_N + t * 84 + j) * 128 + n * 32 + q * 8);
    }

    const int pv_mt = wv & 1;
    const int pv_nb = wv >> 1;
    const int cg = n * 32 + pv_mt * 16 + l15;     // wave-exclusive V channel
    const short* dvaRow = dvaS + ((size_t)b * FF_N + cg) * DI_N;
    const short* ovRow  = ovS + ((size_t)b * FF_N + cg) * OI_N + t * 84;

    f32x4 oacc[3] = {};

    #pragma unroll
    for (int it = 0; it < 7; ++it) {
        const int jc = it * 64;

        // K row direct (wave-exclusive rows; clamp -> finite scores)
        int jg = jc + wv * 16 + l15; if (jg > 419) jg = 419;
        bf16x8 afr = (jg < DI_N)
            ? *reinterpret_cast<const bf16x8*>(
                  dkS + ((size_t)b * DI_N + jg) * 128 + n * 32 + q * 8)
            : *reinterpret_cast<const bf16x8*>(
                  okS + ((size_t)b * OI_N + t * 84 + jg - DI_N) * 128 + n * 32 + q * 8);

        f32x4 s[6];
        #pragma unroll
        for (int nt = 0; nt < 6; ++nt) {
            f32x4 z = {};
            s[nt] = __builtin_amdgcn_mfma_f32_16x16x32_bf16(afr, bfr[nt], z, 0, 0, 0);
        }
        float inv[4];
        #pragma unroll
        for (int r = 0; r < 4; ++r) {
            if (l15 >= 4) s[5][r] = -3.0e38f;     // mask j >= 84
            float m2 = s[0][r];
            #pragma unroll
            for (int nt2 = 1; nt2 < 6; ++nt2) m2 = fmaxf(m2, s[nt2][r]);
            #pragma unroll
            for (int o = 1; o < 16; o <<= 1) m2 = fmaxf(m2, __shfl_xor(m2, o));
            float sm = 0.f;
            #pragma unroll
            for (int nt2 = 0; nt2 < 6; ++nt2) { float e = __expf(s[nt2][r] - m2); s[nt2][r] = e; sm += e; }
            #pragma unroll
            for (int o = 1; o < 16; o <<= 1) sm += __shfl_xor(sm, o);
            inv[r] = 1.f / sm;
        }
        short* Pw = &Pt[it & 1][0];
        const int ibase = jc + wv * 16 + q * 4;   // i of rows r=0..3
        #pragma unroll
        for (int nt = 0; nt < 6; ++nt) {
            short4 pk4;
            pk4.x = (ibase + 0 < CAT_N) ? f2bf(s[nt][0] * inv[0]) : (short)0;
            pk4.y = (ibase + 1 < CAT_N) ? f2bf(s[nt][1] * inv[1]) : (short)0;
            pk4.z = (ibase + 2 < CAT_N) ? f2bf(s[nt][2] * inv[2]) : (short)0;
            pk4.w = (ibase + 3 < CAT_N) ? f2bf(s[nt][3] * inv[3]) : (short)0;
            *reinterpret_cast<short4*>(&Pw[(nt * 16 + l15) * 72 + wv * 16 + q * 4]) = pk4;
        }
        __syncthreads();   // the only barrier: P transpose ready

        #pragma unroll
        for (int kk = 0; kk < 2; ++kk) {
            const int i0 = jc + kk * 32 + q * 8;  // 8-chunk never straddles 336
            bf16x8 va = (i0 < DI_N)
                ? *reinterpret_cast<const bf16x8*>(dvaRow + i0)
                : *reinterpret_cast<const bf16x8*>(ovRow + (i0 - DI_N));
            #pragma unroll
            for (int u = 0; u < 3; ++u) {
                int nt = pv_nb + u * 2;
                bf16x8 pb = *reinterpret_cast<const bf16x8*>(
                    &Pw[(nt * 16 + l15) * 72 + kk * 32 + q * 8]);
                oacc[u] = __builtin_amdgcn_mfma_f32_16x16x32_bf16(va, pb, oacc[u], 0, 0, 0);
            }
        }
    }

    #pragma unroll
    for (int u = 0; u < 3; ++u) {
        int i = (pv_nb + u * 2) * 16 + l15;
        if (i < HW_N) {
            short4 st;
            st.x = f2bf(oacc[u][0]); st.y = f2bf(oacc[u][1]);
            st.z = f2bf(oacc[u][2]); st.w = f2bf(oacc[u][3]);
            *reinterpret_cast<short4*>(
                ovaS + (((size_t)b * OT_N + t) * 84 + i) * 128 + n * 32 + pv_mt * 16 + q * 4) = st;
        }
    }
}

// ---------------- output projection + ReLU + residual (bf16 x) + stats ----
// Wave-autonomous: each wave owns 32 output channels (full K=128 of Wo held
// in 32 VGPRs, loaded once from L2) and streams 48 tokens (3 n-tiles) with
// B-fragments loaded DIRECT from global ova (token-major -> coalesced
// 16B/lane). No LDS staging, no barriers in the compute loop.
__global__ __launch_bounds__(256) void outproj_mfma_kernel(
    short* __restrict__ xbf, const short* __restrict__ ws, int layer,
    float* __restrict__ stats)
{
    __shared__ float redS[4][32];
    __shared__ float redQ[4][32];

    const int bid = blockIdx.x;
    const int t8 = bid & 7;           // XCD id (round-robin dispatch)
    const int rr = bid >> 3;
    const int c32 = rr & 15;          // channel block: 32 chans
    const int tc = rr >> 4;           // 0..13
    const int tchunk = tc * 8 + t8;   // 0..111, 192 tokens each
    const int o0 = c32 * 32;

    const int tid = threadIdx.x;
    const int lane = tid & 63, wv = tid >> 6;
    const int l15 = lane & 15, q = lane >> 4;

    // this wave's 48 tokens (global flat token id over [B][2688])
    const int g0 = tchunk * 192 + wv * 48;
    const int b = g0 / OI_N;                    // 2688 % 192 == 0 -> constant
    const size_t xbase = (size_t)(g0 + DI_N * (b + 1)) * 512 + o0;

    const short* Wo = ws + SW_OWO + layer * 65536;
    const short* ova = ws + S_OVA;

    // weights in registers: afr[mtile][kchunk], row m = o0+mt*16+l15,
    // k elements kc*32 + q*8 .. +8 (matches 16x16x32 A-frag layout)
    bf16x8 afr[2][4];
    #pragma unroll
    for (int mt = 0; mt < 2; ++mt)
        #pragma unroll
        for (int kc = 0; kc < 4; ++kc)
            afr[mt][kc] = *reinterpret_cast<const bf16x8*>(
                Wo + (size_t)(o0 + mt * 16 + l15) * FF_N + kc * 32 + q * 8);

    float csum[2][4] = {}, csq[2][4] = {};

    #pragma unroll
    for (int nt = 0; nt < 3; ++nt) {
        const int g = g0 + nt * 16;
        // B-frag direct from global: row n = token g+l15, k = kc*32 + q*8
        const short* ovaT = ova + (size_t)(g + l15) * FF_N + q * 8;
        bf16x8 bfr[4];
        #pragma unroll
        for (int kc = 0; kc < 4; ++kc)
            bfr[kc] = *reinterpret_cast<const bf16x8*>(ovaT + kc * 32);

        f32x4 acc[2] = {};
        #pragma unroll
        for (int kc = 0; kc < 4; ++kc) {
            acc[0] = __builtin_amdgcn_mfma_f32_16x16x32_bf16(afr[0][kc], bfr[kc], acc[0], 0, 0, 0);
            acc[1] = __builtin_amdgcn_mfma_f32_16x16x32_bf16(afr[1][kc], bfr[kc], acc[1], 0, 0, 0);
        }

        // RMW x: token = g+l15 (acc col), chans o0+mt*16+q*4..+3 (acc rows)
        #pragma unroll
        for (int mt = 0; mt < 2; ++mt) {
            short* p = xbf + xbase + (size_t)(nt * 16 + l15) * 512 + mt * 16 + q * 4;
            short4 old4 = *reinterpret_cast<short4*>(p);
            float ov[4] = {bf2f(old4.x), bf2f(old4.y), bf2f(old4.z), bf2f(old4.w)};
            short4 nw;
            short* nwp = &nw.x;
            #pragma unroll
            for (int r = 0; r < 4; ++r) {
                float v = acc[mt][r];
                float y = ov[r] + (v > 0.f ? v : 0.f);
                short ybf = f2bf(y);
                nwp[r] = ybf;
                float yr = bf2f(ybf);
                csum[mt][r] += yr;
                csq[mt][r] += yr * yr;
            }
            *reinterpret_cast<short4*>(p) = nw;
        }
    }

    // stats: reduce over the 16 token-lanes, then across the 4 waves via LDS
    #pragma unroll
    for (int mt = 0; mt < 2; ++mt) {
        #pragma unroll
        for (int r = 0; r < 4; ++r) {
            float s = csum[mt][r], qq = csq[mt][r];
            #pragma unroll
            for (int o = 1; o < 16; o <<= 1) {
                s += __shfl_xor(s, o);
                qq += __shfl_xor(qq, o);
            }
            if (l15 == 0) {
                redS[wv][mt * 16 + q * 4 + r] = s;
                redQ[wv][mt * 16 + q * 4 + r] = qq;
            }
        }
    }
    __syncthreads();
    if (tid < 32) {
        float s = redS[0][tid] + redS[1][tid] + redS[2][tid] + redS[3][tid];
        float qq = redQ[0][tid] + redQ[1][tid] + redQ[2][tid] + redQ[3][tid];
        atomicAdd(&stats[o0 + tid], s);
        atomicAdd(&stats[512 + o0 + tid], qq);
    }
}

// ---------------- BN in place on bf16 xbf + demo-stats for next layer -----
__global__ __launch_bounds__(256) void bn_mid_kernel(
    short* __restrict__ xbf, const float* __restrict__ stats,
    const float* __restrict__ gamma, const float* __restrict__ beta,
    float* __restrict__ stats_next)
{
    __shared__ float red_s[4][512];
    __shared__ float red_q[4][512];

    const int bid = blockIdx.x;
    const int b = bid / 63, tt = bid % 63;
    const int t0 = tt * 48;
    const bool is_demo = (tt < 7);
    const int tid = threadIdx.x;
    const int chg = tid & 63;
    const int trow = tid >> 6;

    float mean[8], rs[8], g[8], bb[8];
    #pragma unroll
    for (int j = 0; j < 8; ++j) {
        int c = chg * 8 + j;
        float m = stats[c] * INV_CNT;
        float var = stats[512 + c] * INV_CNT - m * m;
        mean[j] = m;
        rs[j] = rsqrtf(var + BN_EPS);
        g[j] = gamma[c];
        bb[j] = beta[c];
    }

    float psum[8] = {}, psq[8] = {};
    #pragma unroll
    for (int it = 0; it < 12; ++it) {
        int tok = t0 + it * 4 + trow;
        short* p = xbf + ((size_t)b * THW_N + tok) * 512 + chg * 8;
        bf16x8 v = *reinterpret_cast<bf16x8*>(p);
        bf16x8 w;
        #pragma unroll
        for (int j = 0; j < 8; ++j) {
            float y = g[j] * (bf2f(v[j]) - mean[j]) * rs[j] + bb[j];
            short yb = f2bf(y);
            w[j] = yb;
            if (is_demo) {
                float yr = bf2f(yb);
                psum[j] += yr; psq[j] += yr * yr;
            }
        }
        *reinterpret_cast<bf16x8*>(p) = w;
    }
    if (!is_demo) return;
    #pragma unroll
    for (int j = 0; j < 8; ++j) {
        red_s[trow][chg * 8 + j] = psum[j];
        red_q[trow][chg * 8 + j] = psq[j];
    }
    __syncthreads();
    #pragma unroll
    for (int h = 0; h < 2; ++h) {
        int c = tid + h * 256;
        float s = red_s[0][c] + red_s[1][c] + red_s[2][c] + red_s[3][c];
        float qq = red_q[0][c] + red_q[1][c] + red_q[2][c] + red_q[3][c];
        atomicAdd(&stats_next[c], s);
        atomicAdd(&stats_next[512 + c], qq);
    }
}

// ---------------- final BN -> fp32 channel-major d_out --------------------
__global__ __launch_bounds__(256) void bn_out_kernel(
    const short* __restrict__ xbf, float* __restrict__ out_f,
    const float* __restrict__ stats,
    const float* __restrict__ gamma, const float* __restrict__ beta)
{
    __shared__ float tile[48][65];

    const int bid = blockIdx.x;
    const int b = bid / 504, rem = bid % 504, tt = rem >> 3, cblk = rem & 7;
    const int t0 = tt * 48, c0 = cblk * 64;
    const int tid = threadIdx.x;
    const int cg = tid & 15;

    float mean[4], rs[4], g[4], bb[4];
    #pragma unroll
    for (int j = 0; j < 4; ++j) {
        int c = c0 + cg * 4 + j;
        float m = stats[c] * INV_CNT;
        float var = stats[512 + c] * INV_CNT - m * m;
        mean[j] = m; rs[j] = rsqrtf(var + BN_EPS);
        g[j] = gamma[c]; bb[j] = beta[c];
    }

    #pragma unroll
    for (int l0 = 0; l0 < 768; l0 += 256) {
        int l = l0 + tid;
        int tok = l >> 4;
        short4 v = *reinterpret_cast<const short4*>(
            xbf + ((size_t)b * THW_N + t0 + tok) * 512 + c0 + cg * 4);
        tile[tok][cg * 4 + 0] = g[0] * (bf2f(v.x) - mean[0]) * rs[0] + bb[0];
        tile[tok][cg * 4 + 1] = g[1] * (bf2f(v.y) - mean[1]) * rs[1] + bb[1];
        tile[tok][cg * 4 + 2] = g[2] * (bf2f(v.z) - mean[2]) * rs[2] + bb[2];
        tile[tok][cg * 4 + 3] = g[3] * (bf2f(v.w) - mean[3]) * rs[3] + bb[3];
    }
    __syncthreads();
    #pragma unroll
    for (int l0 = 0; l0 < 768; l0 += 256) {
        int l = l0 + tid;
        int cc = l / 12, tg = l % 12;
        float4 o;
        o.x = tile[tg * 4 + 0][cc];
        o.y = tile[tg * 4 + 1][cc];
        o.z = tile[tg * 4 + 2][cc];
        o.w = tile[tg * 4 + 3][cc];
        *reinterpret_cast<float4*>(
            out_f + ((size_t)b * D_N + c0 + cc) * THW_N + t0 + tg * 4) = o;
    }
}

// ---------------- launch ----------------
extern "C" void kernel_launch(void* const* d_in, const int* in_sizes, int n_in,
                              void* d_out, int out_size, void* d_ws, size_t ws_size,
                              hipStream_t stream)
{
    const float* inp  = (const float*)d_in[0];
    const float* dwq  = (const float*)d_in[1];
    const float* dwk  = (const float*)d_in[2];
    const float* dwv  = (const float*)d_in[3];
    const float* owq  = (const float*)d_in[5];
    const float* owk  = (const float*)d_in[6];
    const float* owv  = (const float*)d_in[7];
    const float* owo  = (const float*)d_in[8];
    const float* gam  = (const float*)d_in[9];
    const float* bet  = (const float*)d_in[10];
    float* x  = (float*)d_out;
    float* stats = (float*)d_ws;          // [2][1024]
    short* wsS = (short*)(stats + 2048);
    short* xbf = wsS + S_XBF;

    cvt_w_kernel<<<448, 256, 0, stream>>>(dwq, dwk, dwv, owq, owk, owv, owo, wsS, stats);
    xin_kernel<<<4032, 256, 0, stream>>>(inp, xbf, stats);

    for (int layer = 0; layer < 2; ++layer) {
        float* stL = stats + layer * 1024;
        size_t coff = (size_t)layer * D_N;
        proj_mfma_kernel<<<1008, 256, 0, stream>>>(xbf, wsS, layer);
        demo_attn_mfma_kernel<<<256, 192, 0, stream>>>(wsS);
        obs_attn_mfma_kernel<<<1024, 256, 0, stream>>>(wsS);
        outproj_mfma_kernel<<<1792, 256, 0, stream>>>(xbf, wsS, layer, stL);
        if (layer == 0) {
            bn_mid_kernel<<<504, 256, 0, stream>>>(
                xbf, stL, gam + coff, bet + coff, stats + 1024);
        } else {
            bn_out_kernel<<<4032, 256, 0, stream>>>(
                xbf, x, stL, gam + coff, bet + coff);
        }
    }
    (void)in_sizes; (void)n_in; (void)out_size; (void)ws_size;
}